// Round 7
// baseline (4176.590 us; speedup 1.0000x reference)
//
#include <hip/hip_runtime.h>

typedef unsigned int u32;
typedef unsigned short u16;
typedef unsigned long long u64;
typedef float f32x4 __attribute__((ext_vector_type(4)));
typedef short s16x8 __attribute__((ext_vector_type(8)));

#define BIGF 1e9f

__device__ __forceinline__ float b2f(u16 u){ return __uint_as_float(((u32)u) << 16); }
__device__ __forceinline__ u16 f2b(float f){
  u32 x = __float_as_uint(f);
  u32 r = x + 0x7FFFu + ((x >> 16) & 1u);   // RNE
  return (u16)(r >> 16);
}
// scrub: non-finite -> 0 (integer-domain, fast-math-proof)
__device__ __forceinline__ float fin(float v){
  u32 u = __float_as_uint(v);
  return ((u & 0x7F800000u) == 0x7F800000u) ? 0.0f : v;
}
__device__ __forceinline__ bool is_bf(const u32* mraw){ return mraw[0] != 0x3F800000u; }
__device__ __forceinline__ float ldin(const void* p, size_t i, bool bf){
  return bf ? b2f(((const u16*)p)[i]) : ((const float*)p)[i];
}
__device__ __forceinline__ u32 mono32(float f){
  u32 u = __float_as_uint(f);
  return u ^ ((u & 0x80000000u) ? 0xFFFFFFFFu : 0x80000000u);
}
__device__ __forceinline__ u64 umin64(u64 a, u64 b){ return a < b ? a : b; }
__device__ __forceinline__ u32 rotl32(u32 x, int r){ return (x << r) | (x >> (32 - r)); }
__device__ __forceinline__ u32 gp2(u32 u, float g){
  float lo = fin(b2f((u16)(u & 0xFFFFu)) * g), hi = fin(b2f((u16)(u >> 16)) * g);
  return (u32)f2b(lo) | ((u32)f2b(hi) << 16);
}
__device__ __forceinline__ float sigm(float ms){
  return (ms > -30.f) ? 1.0f/(1.0f + __expf(-ms)) : 0.0f;
}

// direct global->LDS async copy, 16 B per lane. LDS dest = base + lane*16 B.
__device__ __forceinline__ void gload_lds16(const u16* gsrc, u16* ldst){
  __builtin_amdgcn_global_load_lds(
      (const __attribute__((address_space(1))) u32*)gsrc,
      (__attribute__((address_space(3))) u32*)ldst, 16, 0, 0);
}

// JAX threefry2x32 (20 rounds), partitionable scheme.
__device__ __forceinline__ void tf2(u32 k0, u32 k1, u32 x0, u32 x1, u32& o0, u32& o1){
  u32 ks2 = k0 ^ k1 ^ 0x1BD11BDAu;
  x0 += k0; x1 += k1;
#define TFR(r) { x0 += x1; x1 = rotl32(x1, (r)); x1 ^= x0; }
  TFR(13) TFR(15) TFR(26) TFR(6)
  x0 += k1; x1 += ks2 + 1u;
  TFR(17) TFR(29) TFR(16) TFR(24)
  x0 += ks2; x1 += k0 + 2u;
  TFR(13) TFR(15) TFR(26) TFR(6)
  x0 += k0; x1 += k1 + 3u;
  TFR(17) TFR(29) TFR(16) TFR(24)
  x0 += k1; x1 += ks2 + 4u;
  TFR(13) TFR(15) TFR(26) TFR(6)
  x0 += ks2; x1 += k0 + 5u;
#undef TFR
  o0 = x0; o1 = x1;
}

// XLA f32 ErfInv (Giles polynomial)
__device__ float erfinv_xla(float x){
#pragma clang fp contract(off)
  float w = -log1pf(-x*x);
  float p;
  if (w < 5.0f){
    w = w - 2.5f;
    p = 2.81022636e-08f;
    p = 3.43273939e-07f + p*w;
    p = -3.5233877e-06f + p*w;
    p = -4.39150654e-06f + p*w;
    p = 0.00021858087f + p*w;
    p = -0.00125372503f + p*w;
    p = -0.00417768164f + p*w;
    p = 0.246640727f + p*w;
    p = 1.50140941f + p*w;
  } else {
    w = sqrtf(w) - 3.0f;
    p = -0.000200214257f;
    p = 0.000100950558f + p*w;
    p = 0.00134934322f + p*w;
    p = -0.00367342844f + p*w;
    p = 0.00573950773f + p*w;
    p = -0.0076224613f + p*w;
    p = 0.00943887047f + p*w;
    p = 1.00167406f + p*w;
    p = 2.83297682f + p*w;
  }
  return p*x;
}

__global__ void k_fallback(void* out, int n, const u32* mraw){
  bool bf = is_bf(mraw);
  int i = blockIdx.x*256 + threadIdx.x;
  if (i < n){ if (bf) ((u16*)out)[i] = f2b(0.125f); else ((float*)out)[i] = 0.125f; }
}

__global__ void k_zero(u32* p, int n){
  int i = blockIdx.x*256 + threadIdx.x;
  if (i < n) p[i] = 0u;
}

// ---------------- input conversion ----------------
__global__ void k_conv(const void* src, float* dst, int n, const u32* mraw){
  bool bf = is_bf(mraw);
  int i = blockIdx.x*256 + threadIdx.x;
  if (i < n) dst[i] = fin(ldin(src, (size_t)i, bf));
}

// R7: all small bias/gain conversions fused into one dispatch; also builds the
// merged QKV bias bqvf[l][768] = [bq | bkv].
__global__ void k_conv_b(const void* s_rs, const void* s_bq, const void* s_bkv,
                         const void* s_bs, const void* s_bc, const void* s_b1,
                         const void* s_b2, const void* s_g1, const void* s_g2,
                         float* rsf, float* bqvf, float* bsf, float* bcf,
                         float* b1f, float* b2f, float* g1f, float* g2f,
                         const u32* mraw){
  bool bf = is_bf(mraw);
  int i = blockIdx.x*256 + threadIdx.x;
  if (i < 1){ rsf[i] = fin(ldin(s_rs, i, bf)); return; }
  i -= 1;
  if (i < 3840){
    int l = i / 768, c = i % 768;
    float v = (c < 256) ? fin(ldin(s_bq, (size_t)l*256 + c, bf))
                        : fin(ldin(s_bkv, (size_t)l*512 + (c - 256), bf));
    bqvf[i] = v; return;
  }
  i -= 3840;
  if (i < 40){ bsf[i] = fin(ldin(s_bs, i, bf)); return; }
  i -= 40;
  if (i < 1280){ bcf[i] = fin(ldin(s_bc, i, bf)); return; }
  i -= 1280;
  if (i < 5120){ b1f[i] = fin(ldin(s_b1, i, bf)); return; }
  i -= 5120;
  if (i < 1280){ b2f[i] = fin(ldin(s_b2, i, bf)); return; }
  i -= 1280;
  if (i < 1280){ g1f[i] = fin(ldin(s_g1, i, bf)); return; }
  i -= 1280;
  if (i < 1280){ g2f[i] = fin(ldin(s_g2, i, bf)); return; }
}

// legacy strided transpose (kept only for tiny Ws: N=8)
__global__ void k_wt(const void* src, u16* dst, int L, int K, int N, const u32* mraw){
  bool bf = is_bf(mraw);
  int i = blockIdx.x*256 + threadIdx.x;
  if (i >= L*K*N) return;
  int l = i/(K*N); int r = i%(K*N); int n = r/K; int k = r%K;
  dst[i] = f2b(fin(ldin(src, (size_t)l*K*N + (size_t)k*N + n, bf)));
}

// R7: coalesced weight transpose via 32x32 LDS tile (old k_wt read at stride N*4B
// = 16x overfetch). dst[l*ostr + (rowoff+n)*K + k] = src[l*K*N + k*N + n].
// REQUIRES K,N multiples of 32.
__global__ void k_wt2(const void* src, u16* dst, int K, int N, int ostr, int rowoff,
                      const u32* mraw){
  bool bf = is_bf(mraw);
  __shared__ float tl[32][33];
  int nt = N >> 5, kt = K >> 5;
  int bid = blockIdx.x;
  int l = bid / (nt*kt); int r2 = bid % (nt*kt);
  int k0 = (r2 / nt) << 5, n0 = (r2 % nt) << 5;
  int tx = threadIdx.x & 31, ty = threadIdx.x >> 5;   // ty in 0..7
  size_t sbase = (size_t)l*K*N;
#pragma unroll
  for (int j = 0; j < 4; ++j){
    int k = k0 + ty + j*8;
    tl[ty + j*8][tx] = fin(ldin(src, sbase + (size_t)k*N + n0 + tx, bf));
  }
  __syncthreads();
#pragma unroll
  for (int j = 0; j < 4; ++j){
    int n = n0 + ty + j*8;
    dst[(size_t)l*ostr + (size_t)(rowoff + n)*K + k0 + tx] = f2b(tl[tx][ty + j*8]);
  }
}

// ---------------- RNG setup ----------------
__global__ void k_rng_setup(float* ABCbuf, u32* pickkeys){
#pragma clang fp contract(off)
  __shared__ float rawn[18][12];
  int s = threadIdx.x;
  if (s < 18){
    u32 ks0, ks1, o0, o1;
    tf2(0u, 42u, 0u, (u32)s, ks0, ks1);
    u32 ka0,ka1,kl0,kl1,kr0,kr1;
    tf2(ks0,ks1, 0u,0u, ka0,ka1);
    tf2(ks0,ks1, 0u,1u, kl0,kl1);
    tf2(ks0,ks1, 0u,2u, kr0,kr1);
    const float MINV = __uint_as_float(0xBF7FFFFFu);
    const float SQ2  = __uint_as_float(0x3FB504F3u);
    for (int j = 0; j < 12; ++j){
      tf2(ka0,ka1, 0u, (u32)j, o0, o1);
      u32 bits = o0 ^ o1;
      float f = __uint_as_float((bits >> 9) | 0x3F800000u) - 1.0f;
      float u = f*2.0f + MINV;
      u = fmaxf(MINV, u);
      rawn[s][j] = SQ2 * erfinv_xla(u);
    }
    u32 a0,a1;
    tf2(kl0,kl1, 0u,0u, a0,a1); pickkeys[(s*4+0)*2]=a0; pickkeys[(s*4+0)*2+1]=a1;
    tf2(kl0,kl1, 0u,1u, a0,a1); pickkeys[(s*4+1)*2]=a0; pickkeys[(s*4+1)*2+1]=a1;
    tf2(kr0,kr1, 0u,0u, a0,a1); pickkeys[(s*4+2)*2]=a0; pickkeys[(s*4+2)*2+1]=a1;
    tf2(kr0,kr1, 0u,1u, a0,a1); pickkeys[(s*4+3)*2]=a0; pickkeys[(s*4+3)*2+1]=a1;
  }
  __syncthreads();
  if (threadIdx.x == 0){
    float oldv[4][3];
    for (int b=0;b<4;b++){ oldv[b][0]=1.f; oldv[b][1]=1.f; oldv[b][2]=1.f; }
    for (int st = 0; st < 18; ++st){
      for (int b = 0; b < 4; ++b){
        float A0 = rawn[st][b*3+0], A1 = rawn[st][b*3+1], A2 = rawn[st][b*3+2];
        float na = fmaxf(sqrtf((A0*A0 + A1*A1) + A2*A2), 1e-12f);
        float p0 = oldv[b][0], p1 = oldv[b][1], p2 = oldv[b][2];
        float no = fmaxf(sqrtf((p0*p0 + p1*p1) + p2*p2), 1e-12f);
        float ang = (A0/na)*(p0/no) + (A1/na)*(p1/no) + (A2/na)*(p2/no);
        float sg = (ang > 0.f) ? 1.f : ((ang < 0.f) ? -1.f : 1.f);
        A0 *= sg; A1 *= sg; A2 *= sg;
        oldv[b][0]=A0; oldv[b][1]=A1; oldv[b][2]=A2;
        ABCbuf[(st*4+b)*3+0]=A0; ABCbuf[(st*4+b)*3+1]=A1; ABCbuf[(st*4+b)*3+2]=A2;
      }
    }
  }
}

__global__ void k_rng_bits(const u32* pickkeys, u32* bits){
  int id = blockIdx.x*256 + threadIdx.x;
  if (id >= 18*4*65536) return;
  int sp = id >> 16; u32 f = (u32)(id & 0xFFFF);
  u32 o0, o1;
  tf2(pickkeys[sp*2], pickkeys[sp*2+1], 0u, f, o0, o1);
  bits[id] = o0 ^ o1;
}

// ---- lightweight single-use PER-BATCH barrier (R7: 16 arrivals, no cross-batch
// convoy; all reductions in k_serialize_coop are per-batch). Slot single-use.
__device__ __forceinline__ void gbar16(u32* slot){
  __syncthreads();
  if (threadIdx.x == 0){
    __hip_atomic_fetch_add(slot, 1u, __ATOMIC_ACQ_REL, __HIP_MEMORY_SCOPE_AGENT);
    while (__hip_atomic_load(slot, __ATOMIC_RELAXED, __HIP_MEMORY_SCOPE_AGENT) < 16u)
      __builtin_amdgcn_s_sleep(2);
    (void)__hip_atomic_load(slot, __ATOMIC_ACQUIRE, __HIP_MEMORY_SCOPE_AGENT);
  }
  __syncthreads();
}

// ---------------- serialization: cooperative, 64 blocks (16 per batch) ----------------
// R4 structure (verified 281 us) + R7 per-batch barriers.
__global__ __launch_bounds__(512) void k_serialize_coop(
    const float* __restrict__ coordsf, const float* __restrict__ maskf,
    const float* __restrict__ ABCbuf, const u32* __restrict__ bits,
    int* __restrict__ tkeys, double* __restrict__ sumpart, int* __restrict__ npart,
    u64* __restrict__ reckey, float4* __restrict__ recxyz, u32* __restrict__ gbars){
#pragma clang fp contract(off)
  __shared__ double sd[8];
  __shared__ int si[8];
  __shared__ u64 sp[4][8];
  int bx = blockIdx.x;
  int b = bx >> 4, blk = bx & 15;
  int t = threadIdx.x, wid = t >> 6, lane = t & 63;
  int base_i = blk*1024;
  u32* gb = gbars + b*64;   // 64 u32 per batch (256B) -> no cross-batch false sharing

  float p[2][3]; int tk[2]; u32 mb = 0;
#pragma unroll
  for (int j = 0; j < 2; ++j){
    int i = base_i + j*512 + t;
    size_t cb = (size_t)(b*16384 + i)*3;
    p[j][0] = coordsf[cb+0]; p[j][1] = coordsf[cb+1]; p[j][2] = coordsf[cb+2];
    if (maskf[b*16384 + i] > 0.f) mb |= (1u << j);
    tk[j] = 0;
  }
  // masked-count block partial (read once after first barrier)
  {
    int c = __popc(mb);
#pragma unroll
    for (int d = 1; d < 64; d <<= 1) c += __shfl_xor(c, d);
    if (lane == 0) si[wid] = c;
    __syncthreads();
    if (t == 0){ int cc = 0; for (int w = 0; w < 8; ++w) cc += si[w]; npart[b*16 + blk] = cc; }
  }
  float nplus = 0.f;

  for (int s = 0; s < 18; ++s){
    float A0 = ABCbuf[(s*4+b)*3+0], A1 = ABCbuf[(s*4+b)*3+1], A2 = ABCbuf[(s*4+b)*3+2];
    // ---- Phase A: projection + masked f64 partial sum ----
    float pr[2]; double acc = 0.0;
#pragma unroll
    for (int j = 0; j < 2; ++j){
      pr[j] = p[j][0]*A0 + p[j][1]*A1 + p[j][2]*A2;
      if ((mb >> j) & 1u) acc += (double)pr[j];
    }
#pragma unroll
    for (int d = 1; d < 64; d <<= 1) acc += __shfl_xor(acc, d);
    if (lane == 0) sd[wid] = acc;
    __syncthreads();
    if (t == 0){ double tt = 0.0; for (int w = 0; w < 8; ++w) tt += sd[w]; sumpart[b*16 + blk] = tt; }
    gbar16(&gb[s*2 + 0]);  // SYNC A (batch-local)

    // ---- Phase B: mean; signs/sides/tk; block argmin records (key + coords) ----
    if (s == 0){
      int cc = 0; for (int k2 = 0; k2 < 16; ++k2) cc += npart[b*16 + k2];
      nplus = (float)((double)cc + 1e-9);
    }
    double tot = 0.0;
    for (int k2 = 0; k2 < 16; ++k2) tot += sumpart[b*16 + k2];
    float mean = ((float)tot) / nplus;

    u32 sideL = 0, sideR = 0;
    int sc17 = 1 << (17 - s);
#pragma unroll
    for (int j = 0; j < 2; ++j){
      float pc = pr[j] - mean;
      int sc = (pc > 0.f) ? 1 : ((pc < 0.f) ? -1 : 0);
      tk[j] += sc * sc17;
      bool mi = (mb >> j) & 1u;
      if (mi && sc < 0) sideL |= (1u << j);
      if (mi && sc > 0) sideR |= (1u << j);
    }
    u64 mine[4]; int bj[4];
#pragma unroll
    for (int pk = 0; pk < 4; ++pk){ mine[pk] = ~0ULL; bj[pk] = 0; }
#pragma unroll
    for (int pk = 0; pk < 4; ++pk){
      const u32* bp = bits + (size_t)(s*4 + pk)*65536 + b*16384;
      u32 sm = (pk < 2) ? sideL : sideR;
#pragma unroll
      for (int j = 0; j < 2; ++j){
        if ((sm >> j) & 1u){
          int i = base_i + j*512 + t;
          u64 pkd = ((u64)(bp[i] >> 9) << 14) | (u32)i;
          if (pkd < mine[pk]){ mine[pk] = pkd; bj[pk] = j; }
        }
      }
    }
    u64 red[4];
#pragma unroll
    for (int pk = 0; pk < 4; ++pk) red[pk] = mine[pk];
#pragma unroll
    for (int d = 1; d < 64; d <<= 1)
#pragma unroll
      for (int pk = 0; pk < 4; ++pk) red[pk] = umin64(red[pk], __shfl_xor(red[pk], d));
    if (lane == 0){
#pragma unroll
      for (int pk = 0; pk < 4; ++pk) sp[pk][wid] = red[pk];
    }
    __syncthreads();
    u64 mm[4];
#pragma unroll
    for (int pk = 0; pk < 4; ++pk){
      u64 v = ~0ULL;
      for (int w = 0; w < 8; ++w) v = umin64(v, sp[pk][w]);
      mm[pk] = v;
    }
#pragma unroll
    for (int pk = 0; pk < 4; ++pk){
      int ri = ((b*4 + pk) << 4) + blk;
      if (mm[pk] == ~0ULL){
        if (t == 0){ reckey[ri] = ~0ULL; recxyz[ri] = make_float4(0.f, 0.f, 0.f, 0.f); }
      } else if (mine[pk] == mm[pk]){
        int j = bj[pk];
        reckey[ri] = mm[pk];
        recxyz[ri] = make_float4(p[j][0], p[j][1], p[j][2], 0.f);
      }
    }
    gbar16(&gb[s*2 + 1]);  // SYNC B (batch-local)

    // ---- Phase C: global argmin over 16 records (coords carried); update points ----
    float wc[4][3];
#pragma unroll
    for (int pk = 0; pk < 4; ++pk){
      u64 best = ~0ULL; int bk = 0;
      for (int k2 = 0; k2 < 16; ++k2){
        u64 kk = reckey[((b*4 + pk) << 4) + k2];
        if (kk < best){ best = kk; bk = k2; }
      }
      float4 c = recxyz[((b*4 + pk) << 4) + bk];
      wc[pk][0] = c.x; wc[pk][1] = c.y; wc[pk][2] = c.z;
    }
    float dl0=(wc[0][0]+wc[1][0])*0.5f, dl1=(wc[0][1]+wc[1][1])*0.5f, dl2=(wc[0][2]+wc[1][2])*0.5f;
    float dr0=(wc[2][0]+wc[3][0])*0.5f, dr1=(wc[2][1]+wc[3][1])*0.5f, dr2=(wc[2][2]+wc[3][2])*0.5f;
#pragma unroll
    for (int j = 0; j < 2; ++j){
      bool L = (sideL >> j) & 1u, R = (sideR >> j) & 1u;
      if (L){ p[j][0]-=dl0; p[j][1]-=dl1; p[j][2]-=dl2; }
      else if (R){ p[j][0]-=dr0; p[j][1]-=dr1; p[j][2]-=dr2; }
      else { p[j][0]=0.f; p[j][1]=0.f; p[j][2]=0.f; }
    }
  }
#pragma unroll
  for (int j = 0; j < 2; ++j){
    int i = base_i + j*512 + t;
    tkeys[b*16384 + i] = tk[j] + (((mb >> j) & 1u) ? 0 : 524288);
  }
}

// ---------------- 16384-element bitonic sort, 3 kernels ----------------
__global__ __launch_bounds__(1024) void k_bsort_phase1(u64* buf){
  __shared__ u64 sb[8192];
  u64* g = buf + (size_t)blockIdx.x*8192;
  int tid = threadIdx.x;
  for (int i = tid; i < 8192; i += 1024) sb[i] = g[i];
  int ab = blockIdx.x & 1;
  for (int k = 2; k <= 8192; k <<= 1){
    for (int j = k >> 1; j > 0; j >>= 1){
      __syncthreads();
      for (int pp = tid; pp < 4096; pp += 1024){
        int i  = ((pp & ~(j - 1)) << 1) | (pp & (j - 1));
        int ix = i | j;
        bool up = (k == 8192) ? (ab == 0) : ((i & k) == 0);
        u64 A = sb[i], B = sb[ix];
        if ((A > B) == up){ sb[i] = B; sb[ix] = A; }
      }
    }
  }
  __syncthreads();
  for (int i = tid; i < 8192; i += 1024) g[i] = sb[i];
}
__global__ __launch_bounds__(1024) void k_bsort_merge(u64* buf){
  u64* g = buf + (size_t)blockIdx.x*16384;
  for (int i = threadIdx.x; i < 8192; i += 1024){
    u64 A = g[i], B = g[i + 8192];
    if (A > B){ g[i] = B; g[i + 8192] = A; }
  }
}
__global__ __launch_bounds__(1024) void k_bsort_phase3(u64* buf){
  __shared__ u64 sb[8192];
  u64* g = buf + (size_t)blockIdx.x*8192;
  int tid = threadIdx.x;
  for (int i = tid; i < 8192; i += 1024) sb[i] = g[i];
  for (int j = 4096; j > 0; j >>= 1){
    __syncthreads();
    for (int pp = tid; pp < 4096; pp += 1024){
      int i  = ((pp & ~(j - 1)) << 1) | (pp & (j - 1));
      int ix = i | j;
      u64 A = sb[i], B = sb[ix];
      if (A > B){ sb[i] = B; sb[ix] = A; }
    }
  }
  __syncthreads();
  for (int i = tid; i < 8192; i += 1024) g[i] = sb[i];
}

__global__ void k_fill_sort(const int* tkeys, u64* sbuf){
  int id = blockIdx.x*256 + threadIdx.x;
  if (id >= 65536) return;
  u32 tv = (u32)(tkeys[id] + 262144);
  sbuf[id] = ((u64)tv << 14) | (u32)(id & 16383);
}
__global__ void k_unpack_sort(const u64* sbuf, int* idxb, int* revb){
  int id = blockIdx.x*256 + threadIdx.x;
  if (id >= 65536) return;
  int a = id >> 14, r = id & 16383;
  int orig = (int)(sbuf[id] & 16383u);
  idxb[id] = orig;
  revb[(a << 14) | orig] = r;
}

// R7: vectorized gather, 4 rows/block (was 66048 blocks x scalar).
__global__ void k_gather(const void* xraw, const int* idxb, float* xbuf, const u32* mraw){
  bool bf = is_bf(mraw);
  int row = blockIdx.x*4 + (threadIdx.x >> 6), lane = threadIdx.x & 63;
  int b = row / 16512, rr = row % 16512;
  float4 v = {0.f, 0.f, 0.f, 0.f};
  if (rr < 16384){
    int src = idxb[b*16384 + rr];
    size_t base = (size_t)(b*16384 + src)*256 + lane*4;
    if (bf){
      ushort4 u = *(const ushort4*)((const u16*)xraw + base);
      v.x = fin(b2f(u.x)); v.y = fin(b2f(u.y)); v.z = fin(b2f(u.z)); v.w = fin(b2f(u.w));
    } else {
      float4 f = *(const float4*)((const float*)xraw + base);
      v.x = fin(f.x); v.y = fin(f.y); v.z = fin(f.z); v.w = fin(f.w);
    }
  }
  *(float4*)&xbuf[(size_t)row*256 + lane*4] = v;
}

__global__ void k_rmsnorm(const float* x, const float* g, u16* xn){
  int row = blockIdx.x*4 + (threadIdx.x >> 6);
  int lane = threadIdx.x & 63;
  float4 xv = *(const float4*)&x[(size_t)row*256 + lane*4];
  xv.x = fin(xv.x); xv.y = fin(xv.y); xv.z = fin(xv.z); xv.w = fin(xv.w);
  float ss = xv.x*xv.x + xv.y*xv.y + xv.z*xv.z + xv.w*xv.w;
#pragma unroll
  for (int d = 1; d < 64; d <<= 1) ss += __shfl_xor(ss, d);
  float sc = 1.0f / sqrtf(ss*(1.0f/256.0f) + 1e-6f);
  float4 gv = *(const float4*)&g[lane*4];
  ushort4 o4;
  o4.x = f2b(fin((xv.x*sc)*gv.x)); o4.y = f2b(fin((xv.y*sc)*gv.y));
  o4.z = f2b(fin((xv.z*sc)*gv.z)); o4.w = f2b(fin((xv.w*sc)*gv.w));
  *(ushort4*)&xn[(size_t)row*256 + lane*4] = o4;
}

// ---------------- bf16 MFMA GEMM: C = A(MxK) * Bt(NxK)^T + bias ----------------
// mode 0: f32 store; 1: f32 X += v*rs; 2: bf16 store; 3: gelu->bf16;
// 4: QKV split (col<256 -> C as qb ldc256 bf16, else C2 as vkv ldc512 bf16)
// R6 verified: global_load_lds staging + both-sides XOR swizzle (T2/rule#21) + XCD swizzle.
// REQUIRES: M,N multiples of 128; K multiple of 64.
__global__ __launch_bounds__(256) void k_gemm(const u16* A, int lda, const u16* Bt, int ldb,
                                              int M, int N, int K, const float* bias,
                                              void* C, int ldc, int mode, const float* rsp,
                                              void* C2){
  __shared__ __align__(16) u16 As[128*64];
  __shared__ __align__(16) u16 Bs[128*64];
  int tid = threadIdx.x;
  // --- XCD-aware bijective remap of the flat workgroup id ---
  int gx = (int)gridDim.x;
  int nwg = gx * (int)gridDim.y;
  int d = (int)blockIdx.y * gx + (int)blockIdx.x;   // dispatch-order flat id (x fastest)
  int q = nwg >> 3, r = nwg & 7;
  int xcd = d & 7, off = d >> 3;
  int wg = (xcd < r ? xcd*(q+1) : r*(q+1) + (xcd - r)*q) + off;
  int bxi = wg % gx, byi = wg / gx;
  int gm0 = byi*128, gn0 = bxi*128;
  int wv = tid >> 6, lane = tid & 63, q4 = lane >> 4, l16 = lane & 15;
  int wm = (wv >> 1)*64, wn = (wv & 1)*64;
  int lr = lane >> 3;
  int lcs = ((lane & 7) ^ lr) << 3;          // swizzled SOURCE col (u16)
  f32x4 acc[4][4];
#pragma unroll
  for (int i = 0; i < 4; ++i)
#pragma unroll
    for (int j = 0; j < 4; ++j) acc[i][j] = (f32x4){0.f,0.f,0.f,0.f};
  for (int k0 = 0; k0 < K; k0 += 64){
    __syncthreads();
#pragma unroll
    for (int i = 0; i < 4; ++i){
      int chunk = wv*4 + i;                  // 16 chunks of 8 rows
      int row = chunk*8 + lr;
      gload_lds16(&A[(size_t)(gm0+row)*lda + k0 + lcs],  &As[chunk*512]);
      gload_lds16(&Bt[(size_t)(gn0+row)*ldb + k0 + lcs], &Bs[chunk*512]);
    }
    __syncthreads();   // compiler drains vmcnt before s_barrier
#pragma unroll
    for (int ks = 0; ks < 64; ks += 32){
      int swc = ((((ks >> 3) + q4) ^ (l16 & 7)) << 3);
      s16x8 aF[4], bF[4];
#pragma unroll
      for (int mt = 0; mt < 4; ++mt) aF[mt] = *(const s16x8*)&As[(wm + mt*16 + l16)*64 + swc];
#pragma unroll
      for (int nt = 0; nt < 4; ++nt) bF[nt] = *(const s16x8*)&Bs[(wn + nt*16 + l16)*64 + swc];
#pragma unroll
      for (int mt = 0; mt < 4; ++mt)
#pragma unroll
        for (int nt = 0; nt < 4; ++nt)
          acc[mt][nt] = __builtin_amdgcn_mfma_f32_16x16x32_bf16(aF[mt], bF[nt], acc[mt][nt], 0, 0, 0);
    }
  }
  float rs = rsp[0];
  const float SQ2C = 1.41421356237f;
#pragma unroll
  for (int mt = 0; mt < 4; ++mt)
#pragma unroll
    for (int nt = 0; nt < 4; ++nt){
      int col = gn0 + wn + nt*16 + l16;
      float bi = bias[col];
#pragma unroll
      for (int rg = 0; rg < 4; ++rg){
        int row = gm0 + wm + mt*16 + q4*4 + rg;
        float v = fin(acc[mt][nt][rg] + bi);
        size_t off2 = (size_t)row*ldc + col;
        if (mode == 0) ((float*)C)[off2] = v;
        else if (mode == 1){ float* X = (float*)C; X[off2] = fin(X[off2] + v*rs); }
        else if (mode == 2) ((u16*)C)[off2] = f2b(v);
        else if (mode == 3){ float gl = 0.5f * v * (1.0f + erff(v / SQ2C)); ((u16*)C)[off2] = f2b(fin(gl)); }
        else {
          if (col < 256) ((u16*)C)[(size_t)row*256 + col] = f2b(v);
          else ((u16*)C2)[(size_t)row*512 + (col - 256)] = f2b(v);
        }
      }
    }
}

// ---------------- score GEMM: C[M][8] = A[M][256] * Ws[8][256]^T + bias (f32) ------
__global__ __launch_bounds__(256) void k_gemm_score(const u16* __restrict__ A,
                                                    const u16* __restrict__ Bt,
                                                    int M, const float* __restrict__ bias,
                                                    float* __restrict__ C){
  __shared__ __align__(16) u16 As[128*72];
  int tid = threadIdx.x;
  int gm0 = blockIdx.x*128;
  int wv = tid >> 6, lane = tid & 63, q4 = lane >> 4, l16 = lane & 15;
  int wm = wv*32;                  // 4 waves x 32 rows
  int ar = tid >> 2, ac = tid & 3;
  f32x4 acc[2];
  acc[0] = (f32x4){0.f,0.f,0.f,0.f};
  acc[1] = (f32x4){0.f,0.f,0.f,0.f};
  for (int k0 = 0; k0 < 256; k0 += 64){
    __syncthreads();
#pragma unroll
    for (int ps = 0; ps < 2; ++ps){
      int r2 = ps*64 + ar;
      uint4 va0 = {0u,0u,0u,0u}, va1 = {0u,0u,0u,0u};
      if (gm0 + r2 < M){
        const u16* ap = &A[(size_t)(gm0+r2)*256 + k0 + ac*16];
        va0 = ((const uint4*)ap)[0];
        va1 = ((const uint4*)ap)[1];
      }
      *(uint4*)&As[r2*72 + ac*16]     = va0;
      *(uint4*)&As[r2*72 + ac*16 + 8] = va1;
    }
    __syncthreads();
#pragma unroll
    for (int ks = 0; ks < 64; ks += 32){
      s16x8 bF = (s16x8){0,0,0,0,0,0,0,0};
      if (l16 < 8) bF = *(const s16x8*)&Bt[(size_t)l16*256 + k0 + ks + q4*8];
      s16x8 aF0 = *(const s16x8*)&As[(wm + l16)*72 + ks + q4*8];
      s16x8 aF1 = *(const s16x8*)&As[(wm + 16 + l16)*72 + ks + q4*8];
      acc[0] = __builtin_amdgcn_mfma_f32_16x16x32_bf16(aF0, bF, acc[0], 0, 0, 0);
      acc[1] = __builtin_amdgcn_mfma_f32_16x16x32_bf16(aF1, bF, acc[1], 0, 0, 0);
    }
  }
  if (l16 < 8){
    float bi = bias[l16];
#pragma unroll
    for (int mt = 0; mt < 2; ++mt)
#pragma unroll
      for (int rg = 0; rg < 4; ++rg){
        int row = gm0 + wm + mt*16 + q4*4 + rg;
        if (row < M) C[(size_t)row*8 + l16] = fin(acc[mt][rg] + bi);
      }
  }
}

// ---------------- selection: local (drop 1 of 129) ----------------
__global__ __launch_bounds__(512) void k_sel_local(const float* scoreb, const float* maskf,
                                                   u32* sel, float* gateb){
  int s = blockIdx.x, h = threadIdx.x >> 6, lane = threadIdx.x & 63;
  int b = s >> 7, tt = s & 127;
  u64 pm = ~0ULL;
  for (int rep = 0; rep < 3; ++rep){
    int j = lane + rep*64;
    if (j < 129){
      int p = tt*129 + j;
      float m = (p < 16384) ? maskf[b*16384 + p] : 0.f;
      float ms = fin(scoreb[(size_t)(s*129 + j)*8 + h]) - (1.0f - m)*BIGF;
      u64 pk = ((u64)mono32(ms) << 9) | (u32)(511 - j);  // min val; tie -> drop larger j
      pm = umin64(pm, pk);
    }
  }
#pragma unroll
  for (int d = 1; d < 64; d <<= 1) pm = umin64(pm, __shfl_xor(pm, d));
  int dropped = 511 - (int)(pm & 511u);
  int sh = s*8 + h;
  for (int rep = 0; rep < 3; ++rep){
    int j = lane + rep*64;
    if (j < 129 && j != dropped){
      int slot = j - (j > dropped ? 1 : 0);
      int p = tt*129 + j;
      float m = (p < 16384) ? maskf[b*16384 + p] : 0.f;
      float ms = fin(scoreb[(size_t)(s*129 + j)*8 + h]) - (1.0f - m)*BIGF;
      sel[sh*128 + slot] = (u32)(s*129 + j);
      gateb[sh*128 + slot] = fin(sigm(ms));
    }
  }
}

// selection: global (top-128 of 16384 via sorted keys)
__global__ void k_fill_topk(const float* scoreb, const float* maskf, u64* sbuf){
  int id = blockIdx.x*256 + threadIdx.x;
  if (id >= 524288) return;
  int arr = id >> 14, i = id & 16383;
  int b = arr >> 3, h = arr & 7;
  float m = maskf[b*16384 + i];
  float ms = fin(scoreb[(size_t)(b*16512 + i)*8 + h]) - (1.0f - m)*BIGF;
  sbuf[id] = ((u64)(~mono32(ms)) << 14) | (u32)i;  // descending val, tie -> lower i
}
__global__ void k_sel_gemit(const u64* sbuf, const float* scoreb, const float* maskf,
                            u32* sel, float* gateb){
  int arr = blockIdx.x, tid = threadIdx.x;  // 32 x 128
  int b = arr >> 3, h = arr & 7;
  int j = (int)(sbuf[(size_t)arr*16384 + tid] & 16383u);
  float m = maskf[b*16384 + j];
  float ms = fin(scoreb[(size_t)(b*16512 + j)*8 + h]) - (1.0f - m)*BIGF;
  sel[arr*128 + tid] = (u32)(b*16512 + j);
  gateb[arr*128 + tid] = fin(sigm(ms));
}

// ---------------- fused MFMA attention (gathers gated K/V from vkv) ----------------
__global__ __launch_bounds__(256) void k_attn(const u16* qb, const u16* vkv,
                                              const u32* sel, const float* gateb,
                                              u16* xa, int gmode){
  __shared__ __align__(16) u16 Qsm[144*40];
  __shared__ __align__(16) u16 Ksm[128*40];
  __shared__ __align__(16) u16 Vtsm[32*136];
  __shared__ __align__(16) u16 Psm[4*16*136];
  int tid = threadIdx.x;
  int bx = blockIdx.x, h = blockIdx.y;
  int rows, rowbase, kvs, ntiles;
  if (gmode){
    int b = bx >> 7, rb = bx & 127;
    rows = 128; rowbase = b*16512 + rb*128; kvs = b; ntiles = 8;
  } else {
    rows = 129; rowbase = bx*129; kvs = bx; ntiles = 9;
  }
  int sh = kvs*8 + h;
  for (int t = tid; t < 144; t += 256) *(uint4*)&Qsm[t*40 + 32] = (uint4){0u,0u,0u,0u};
  if (tid < 128) *(uint4*)&Ksm[tid*40 + 32] = (uint4){0u,0u,0u,0u};
  if (tid < 32)  *(uint4*)&Vtsm[tid*136 + 128] = (uint4){0u,0u,0u,0u};
  if (tid < 64)  *(uint4*)&Psm[tid*136 + 128] = (uint4){0u,0u,0u,0u};
  for (int t = tid; t < 576; t += 256){
    int r = t >> 2, c = t & 3;
    uint4 v = {0u,0u,0u,0u};
    if (r < rows) v = *(const uint4*)&qb[(size_t)(rowbase + r)*256 + h*32 + c*8];
    *(uint4*)&Qsm[r*40 + c*8] = v;
  }
  for (int t = tid; t < 512; t += 256){
    int slot = t >> 2, part = t & 3;
    u32 rowi = sel[sh*128 + slot];
    float gv = fin(gateb[sh*128 + slot]);
    uint4 vk = *(const uint4*)&vkv[(size_t)rowi*512 + h*64 + part*8];
    uint4 wk; wk.x = gp2(vk.x, gv); wk.y = gp2(vk.y, gv); wk.z = gp2(vk.z, gv); wk.w = gp2(vk.w, gv);
    *(uint4*)&Ksm[slot*40 + part*8] = wk;
    uint4 vv = *(const uint4*)&vkv[(size_t)rowi*512 + h*64 + 32 + part*8];
    u32 vd[4] = {vv.x, vv.y, vv.z, vv.w};
#pragma unroll
    for (int e = 0; e < 4; ++e){
      float lo = fin(b2f((u16)(vd[e] & 0xFFFFu)) * gv), hi = fin(b2f((u16)(vd[e] >> 16)) * gv);
      Vtsm[(part*8 + e*2 + 0)*136 + slot] = f2b(lo);
      Vtsm[(part*8 + e*2 + 1)*136 + slot] = f2b(hi);
    }
  }
  __syncthreads();
  int wv = tid >> 6, lane = tid & 63, q4 = lane >> 4, l16 = lane & 15;
  u16* Pw = Psm + wv*(16*136);
  const float ATTSC = 0.17677669529663689f;
  f32x4 z = {0.f,0.f,0.f,0.f};
  for (int mt = wv; mt < ntiles; mt += 4){
    int m0 = mt*16;
    s16x8 aQ = *(const s16x8*)&Qsm[(m0 + l16)*40 + q4*8];
    f32x4 S[8];
#pragma unroll
    for (int nt = 0; nt < 8; ++nt){
      s16x8 bK = *(const s16x8*)&Ksm[(nt*16 + l16)*40 + q4*8];
      S[nt] = __builtin_amdgcn_mfma_f32_16x16x32_bf16(aQ, bK, z, 0, 0, 0);
    }
    float mx[4] = {-1e30f,-1e30f,-1e30f,-1e30f};
#pragma unroll
    for (int nt = 0; nt < 8; ++nt)
#pragma unroll
      for (int rg = 0; rg < 4; ++rg){ float v = fin(S[nt][rg])*ATTSC; S[nt][rg] = v; mx[rg] = fmaxf(mx[rg], v); }
#pragma unroll
    for (int d = 1; d < 16; d <<= 1)
#pragma unroll
      for (int rg = 0; rg < 4; ++rg) mx[rg] = fmaxf(mx[rg], __shfl_xor(mx[rg], d));
    float sm[4] = {0.f,0.f,0.f,0.f};
#pragma unroll
    for (int nt = 0; nt < 8; ++nt)
#pragma unroll
      for (int rg = 0; rg < 4; ++rg){ float e = __expf(S[nt][rg] - mx[rg]); S[nt][rg] = e; sm[rg] += e; }
#pragma unroll
    for (int d = 1; d < 16; d <<= 1)
#pragma unroll
      for (int rg = 0; rg < 4; ++rg) sm[rg] += __shfl_xor(sm[rg], d);
    float inv[4];
#pragma unroll
    for (int rg = 0; rg < 4; ++rg) inv[rg] = 1.0f/fmaxf(sm[rg], 1e-20f);
#pragma unroll
    for (int nt = 0; nt < 8; ++nt)
#pragma unroll
      for (int rg = 0; rg < 4; ++rg)
        Pw[(q4*4 + rg)*136 + nt*16 + l16] = f2b(fin(S[nt][rg]*inv[rg]));
    f32x4 O0 = z, O1 = z;
#pragma unroll
    for (int kq = 0; kq < 4; ++kq){
      s16x8 aP = *(const s16x8*)&Pw[l16*136 + kq*32 + q4*8];
      s16x8 b0 = *(const s16x8*)&Vtsm[l16*136 + kq*32 + q4*8];
      s16x8 b1 = *(const s16x8*)&Vtsm[(16 + l16)*136 + kq*32 + q4*8];
      O0 = __builtin_amdgcn_mfma_f32_16x16x32_bf16(aP, b0, O0, 0, 0, 0);
      O1 = __builtin_amdgcn_mfma_f32_16x16x32_bf16(aP, b1, O1, 0, 0, 0);
    }
#pragma unroll
    for (int rg = 0; rg < 4; ++rg){
      int r = m0 + q4*4 + rg;
      if (r < rows){
        size_t base = (size_t)(rowbase + r)*256 + h*32;
        xa[base + l16] = f2b(fin(O0[rg]));
        xa[base + 16 + l16] = f2b(fin(O1[rg]));
      }
    }
  }
}

// R7: vectorized output, 4 rows/block (was 65536 blocks x scalar).
__global__ void k_output(const float* xbuf, const int* revb, void* out, const u32* mraw){
  bool bf = is_bf(mraw);
  int row = blockIdx.x*4 + (threadIdx.x >> 6), lane = threadIdx.x & 63;
  int b = row >> 14;
  int rank = revb[row];
  float4 f = *(const float4*)&xbuf[(size_t)(b*16512 + rank)*256 + lane*4];
  f.x = fin(f.x); f.y = fin(f.y); f.z = fin(f.z); f.w = fin(f.w);
  if (bf){
    ushort4 u; u.x = f2b(f.x); u.y = f2b(f.y); u.z = f2b(f.z); u.w = f2b(f.w);
    *(ushort4*)((u16*)out + (size_t)row*256 + lane*4) = u;
  } else {
    *(float4*)((float*)out + (size_t)row*256 + lane*4) = f;
  }
}

// =========================== host ===========================
extern "C" void kernel_launch(void* const* d_in, const int* in_sizes, int n_in,
                              void* d_out, int out_size, void* d_ws, size_t ws_size,
                              hipStream_t stream){
  (void)in_sizes; (void)n_in;
  const u32* mraw = (const u32*)d_in[2];
  char* wsp = (char*)d_ws;
  size_t o = 0;
  auto alloc = [&](size_t bytes)->void*{ void* p = (void*)(wsp + o); o += (bytes + 255) & ~(size_t)255; return p; };
  float* maskf   = (float*)alloc(65536u*4);
  float* coordsf = (float*)alloc(196608u*4);
  float* rsf     = (float*)alloc(256);
  float* bqvf    = (float*)alloc(5*768*4);
  float* bsf     = (float*)alloc(5*8*4);
  float* bcf     = (float*)alloc(5*256*4);
  float* b1f     = (float*)alloc(5*1024*4);
  float* b2f     = (float*)alloc(5*256*4);
  float* g1f     = (float*)alloc(5*256*4);
  float* g2f     = (float*)alloc(5*256*4);
  u16* WqvT = (u16*)alloc((size_t)5*768*256*2);
  u16* WsT  = (u16*)alloc((size_t)5*8*256*2);
  u16* WcT  = (u16*)alloc((size_t)5*256*256*2);
  u16* W1T  = (u16*)alloc((size_t)5*1024*256*2);
  u16* W2T  = (u16*)alloc((size_t)5*1024*256*2);
  float* ABCbuf = (float*)alloc(18*12*4);
  u32* pickkeys = (u32*)alloc(72*2*4);
  int* tkeys = (int*)alloc(65536u*4);
  int* idxb  = (int*)alloc(65536u*4);
  int* revb  = (int*)alloc(65536u*4);
  double* sumpart = (double*)alloc(64*8);
  int*    npart   = (int*)alloc(64*4);
  u64*    reckey  = (u64*)alloc(256*8);
  float4* recxyz  = (float4*)alloc(256*16);
  u32*    gbars   = (u32*)alloc(256*4);
  u64* sortbuf = (u64*)alloc((size_t)32*16384*8);
  float* xbuf = (float*)alloc((size_t)66048*256*4);
  u16* xn  = (u16*)alloc((size_t)66048*256*2);
  float* scoreb = (float*)alloc((size_t)66048*8*4);
  const size_t SZ_VKV = (size_t)66048*512*2;
  const size_t SZ_QB  = (size_t)66048*256*2;
  const size_t SZ_SEL = (size_t)4096*128*4;
  char* Sbase = (char*)alloc(SZ_VKV + SZ_QB + 2*SZ_SEL);
  u16* vkv    = (u16*)Sbase;
  u16* qb     = (u16*)(Sbase + SZ_VKV);
  u32* sel    = (u32*)(Sbase + SZ_VKV + SZ_QB);
  float* gateb= (float*)(Sbase + SZ_VKV + SZ_QB + SZ_SEL);
  u32* bitsb  = (u32*)Sbase;
  u16* ffb    = (u16*)Sbase;
  u16* xa     = qb;

  if (o > ws_size){
    k_fallback<<<dim3((out_size + 255)/256), 256, 0, stream>>>(d_out, out_size, mraw);
    return;
  }

  k_conv<<<dim3(256), 256, 0, stream>>>(d_in[2], maskf, 65536, mraw);
  k_conv<<<dim3(768), 256, 0, stream>>>(d_in[1], coordsf, 196608, mraw);
  k_conv_b<<<dim3(56), 256, 0, stream>>>(d_in[3], d_in[5], d_in[7], d_in[15], d_in[9],
                                         d_in[11], d_in[13], d_in[16], d_in[17],
                                         rsf, bqvf, bsf, bcf, b1f, b2f, g1f, g2f, mraw);
  // coalesced transposes (K,N multiples of 32); Ws (N=8) keeps the legacy path
  k_wt2<<<dim3(5*8*8),  256, 0, stream>>>(d_in[4],  WqvT, 256, 256,  768*256, 0,   mraw);
  k_wt2<<<dim3(5*8*16), 256, 0, stream>>>(d_in[6],  WqvT, 256, 512,  768*256, 256, mraw);
  k_wt2<<<dim3(5*8*8),  256, 0, stream>>>(d_in[8],  WcT,  256, 256,  256*256, 0,   mraw);
  k_wt2<<<dim3(5*8*32), 256, 0, stream>>>(d_in[10], W1T,  256, 1024, 1024*256, 0,  mraw);
  k_wt2<<<dim3(5*32*8), 256, 0, stream>>>(d_in[12], W2T,  1024, 256, 256*1024, 0,  mraw);
  k_wt<<<dim3(40), 256, 0, stream>>>(d_in[14], WsT, 5, 256, 8, mraw);

  k_rng_setup<<<dim3(1), 64, 0, stream>>>(ABCbuf, pickkeys);
  k_rng_bits<<<dim3(18432), 256, 0, stream>>>(pickkeys, bitsb);
  k_zero<<<dim3(1), 256, 0, stream>>>(gbars, 256);
  {
    const float* a_coords = coordsf;
    const float* a_mask   = maskf;
    const float* a_abc    = ABCbuf;
    const u32*   a_bits   = bitsb;
    int*         a_tkeys  = tkeys;
    double*      a_sum    = sumpart;
    int*         a_np     = npart;
    u64*         a_rk     = reckey;
    float4*      a_rx     = recxyz;
    u32*         a_gb     = gbars;
    void* kargs[10];
    kargs[0] = (void*)&a_coords; kargs[1] = (void*)&a_mask; kargs[2] = (void*)&a_abc;
    kargs[3] = (void*)&a_bits;   kargs[4] = (void*)&a_tkeys;
    kargs[5] = (void*)&a_sum;    kargs[6] = (void*)&a_np;
    kargs[7] = (void*)&a_rk;     kargs[8] = (void*)&a_rx;
    kargs[9] = (void*)&a_gb;
    hipLaunchCooperativeKernel((void*)k_serialize_coop, dim3(64), dim3(512), kargs, 0, stream);
  }
  k_fill_sort<<<dim3(256), 256, 0, stream>>>(tkeys, sortbuf);
  k_bsort_phase1<<<dim3(8), 1024, 0, stream>>>(sortbuf);
  k_bsort_merge<<<dim3(4), 1024, 0, stream>>>(sortbuf);
  k_bsort_phase3<<<dim3(8), 1024, 0, stream>>>(sortbuf);
  k_unpack_sort<<<dim3(256), 256, 0, stream>>>(sortbuf, idxb, revb);
  k_gather<<<dim3(16512), 256, 0, stream>>>(d_in[0], idxb, xbuf, mraw);

  auto gemm = [&](const u16* A, int lda, const u16* Bt, int ldb, int M, int N, int K,
                  const float* bias, void* C, int ldc, int mode){
    dim3 g((N + 127)/128, (M + 127)/128);
    k_gemm<<<g, 256, 0, stream>>>(A, lda, Bt, ldb, M, N, K, bias, C, ldc, mode, rsf, (void*)0);
  };

  for (int l = 0; l < 5; ++l){
    bool local = (l < 4);
    k_rmsnorm<<<dim3(16512), 256, 0, stream>>>(xbuf, g1f + l*256, xn);
    // merged Q+KV GEMM (N=768, mode 4 split epilogue)
    {
      dim3 g(6, 516);
      k_gemm<<<g, 256, 0, stream>>>(xn, 256, WqvT + (size_t)l*768*256, 256,
                                    66048, 768, 256, bqvf + l*768,
                                    qb, 0, 4, rsf, (void*)vkv);
    }
    k_gemm_score<<<dim3(516), 256, 0, stream>>>(xn, WsT + (size_t)l*8*256, 66048,
                                                bsf + l*8, scoreb);
    if (local){
      k_sel_local<<<dim3(512), 512, 0, stream>>>(scoreb, maskf, sel, gateb);
    } else {
      k_fill_topk<<<dim3(2048), 256, 0, stream>>>(scoreb, maskf, sortbuf);
      k_bsort_phase1<<<dim3(64), 1024, 0, stream>>>(sortbuf);
      k_bsort_merge<<<dim3(32), 1024, 0, stream>>>(sortbuf);
      k_bsort_phase3<<<dim3(64), 1024, 0, stream>>>(sortbuf);
      k_sel_gemit<<<dim3(32), 128, 0, stream>>>(sortbuf, scoreb, maskf, sel, gateb);
    }
    k_attn<<<dim3(512, 8), 256, 0, stream>>>(qb, vkv, sel, gateb, xa, local ? 0 : 1);
    gemm(xa, 256, WcT + (size_t)l*256*256, 256, 66048, 256, 256, bcf + l*256, xbuf, 256, 1);
    k_rmsnorm<<<dim3(16512), 256, 0, stream>>>(xbuf, g2f + l*256, xn);
    for (int half = 0; half < 2; ++half){
      const u16* Ah = xn + (size_t)half*33024*256;
      gemm(Ah, 256, W1T + (size_t)l*1024*256, 256, 33024, 1024, 256, b1f + l*1024, ffb, 1024, 3);
      gemm(ffb, 1024, W2T + (size_t)l*1024*256, 1024, 33024, 256, 1024, b2f + l*256,
           xbuf + (size_t)half*33024*256, 256, 1);
    }
  }
  k_output<<<dim3(16384), 256, 0, stream>>>(xbuf, revb, d_out, mraw);
}

// Round 8
// 3391.592 us; speedup vs baseline: 1.2315x; 1.2315x over previous
//
#include <hip/hip_runtime.h>

typedef unsigned int u32;
typedef unsigned short u16;
typedef unsigned long long u64;
typedef float f32x4 __attribute__((ext_vector_type(4)));
typedef short s16x8 __attribute__((ext_vector_type(8)));

#define BIGF 1e9f

__device__ __forceinline__ float b2f(u16 u){ return __uint_as_float(((u32)u) << 16); }
__device__ __forceinline__ u16 f2b(float f){
  u32 x = __float_as_uint(f);
  u32 r = x + 0x7FFFu + ((x >> 16) & 1u);   // RNE
  return (u16)(r >> 16);
}
// scrub: non-finite -> 0 (integer-domain, fast-math-proof)
__device__ __forceinline__ float fin(float v){
  u32 u = __float_as_uint(v);
  return ((u & 0x7F800000u) == 0x7F800000u) ? 0.0f : v;
}
__device__ __forceinline__ bool is_bf(const u32* mraw){ return mraw[0] != 0x3F800000u; }
__device__ __forceinline__ float ldin(const void* p, size_t i, bool bf){
  return bf ? b2f(((const u16*)p)[i]) : ((const float*)p)[i];
}
__device__ __forceinline__ u32 mono32(float f){
  u32 u = __float_as_uint(f);
  return u ^ ((u & 0x80000000u) ? 0xFFFFFFFFu : 0x80000000u);
}
__device__ __forceinline__ u64 umin64(u64 a, u64 b){ return a < b ? a : b; }
__device__ __forceinline__ u32 rotl32(u32 x, int r){ return (x << r) | (x >> (32 - r)); }
__device__ __forceinline__ u32 gp2(u32 u, float g){
  float lo = fin(b2f((u16)(u & 0xFFFFu)) * g), hi = fin(b2f((u16)(u >> 16)) * g);
  return (u32)f2b(lo) | ((u32)f2b(hi) << 16);
}
__device__ __forceinline__ float sigm(float ms){
  return (ms > -30.f) ? 1.0f/(1.0f + __expf(-ms)) : 0.0f;
}

// direct global->LDS async copy, 16 B per lane. LDS dest = base + lane*16 B.
__device__ __forceinline__ void gload_lds16(const u16* gsrc, u16* ldst){
  __builtin_amdgcn_global_load_lds(
      (const __attribute__((address_space(1))) u32*)gsrc,
      (__attribute__((address_space(3))) u32*)ldst, 16, 0, 0);
}

// JAX threefry2x32 (20 rounds), partitionable scheme.
__device__ __forceinline__ void tf2(u32 k0, u32 k1, u32 x0, u32 x1, u32& o0, u32& o1){
  u32 ks2 = k0 ^ k1 ^ 0x1BD11BDAu;
  x0 += k0; x1 += k1;
#define TFR(r) { x0 += x1; x1 = rotl32(x1, (r)); x1 ^= x0; }
  TFR(13) TFR(15) TFR(26) TFR(6)
  x0 += k1; x1 += ks2 + 1u;
  TFR(17) TFR(29) TFR(16) TFR(24)
  x0 += ks2; x1 += k0 + 2u;
  TFR(13) TFR(15) TFR(26) TFR(6)
  x0 += k0; x1 += k1 + 3u;
  TFR(17) TFR(29) TFR(16) TFR(24)
  x0 += k1; x1 += ks2 + 4u;
  TFR(13) TFR(15) TFR(26) TFR(6)
  x0 += ks2; x1 += k0 + 5u;
#undef TFR
  o0 = x0; o1 = x1;
}

// XLA f32 ErfInv (Giles polynomial)
__device__ float erfinv_xla(float x){
#pragma clang fp contract(off)
  float w = -log1pf(-x*x);
  float p;
  if (w < 5.0f){
    w = w - 2.5f;
    p = 2.81022636e-08f;
    p = 3.43273939e-07f + p*w;
    p = -3.5233877e-06f + p*w;
    p = -4.39150654e-06f + p*w;
    p = 0.00021858087f + p*w;
    p = -0.00125372503f + p*w;
    p = -0.00417768164f + p*w;
    p = 0.246640727f + p*w;
    p = 1.50140941f + p*w;
  } else {
    w = sqrtf(w) - 3.0f;
    p = -0.000200214257f;
    p = 0.000100950558f + p*w;
    p = 0.00134934322f + p*w;
    p = -0.00367342844f + p*w;
    p = 0.00573950773f + p*w;
    p = -0.0076224613f + p*w;
    p = 0.00943887047f + p*w;
    p = 1.00167406f + p*w;
    p = 2.83297682f + p*w;
  }
  return p*x;
}

__global__ void k_fallback(void* out, int n, const u32* mraw){
  bool bf = is_bf(mraw);
  int i = blockIdx.x*256 + threadIdx.x;
  if (i < n){ if (bf) ((u16*)out)[i] = f2b(0.125f); else ((float*)out)[i] = 0.125f; }
}

__global__ void k_zero(u32* p, int n){
  int i = blockIdx.x*256 + threadIdx.x;
  if (i < n) p[i] = 0u;
}

// ---------------- input conversion ----------------
__global__ void k_conv(const void* src, float* dst, int n, const u32* mraw){
  bool bf = is_bf(mraw);
  int i = blockIdx.x*256 + threadIdx.x;
  if (i < n) dst[i] = fin(ldin(src, (size_t)i, bf));
}

// R7 (kept): all small bias/gain conversions fused into one dispatch (separate outputs).
__global__ void k_conv_b(const void* s_rs, const void* s_bq, const void* s_bkv,
                         const void* s_bs, const void* s_bc, const void* s_b1,
                         const void* s_b2, const void* s_g1, const void* s_g2,
                         float* rsf, float* bqf, float* bkvf, float* bsf, float* bcf,
                         float* b1f, float* b2f, float* g1f, float* g2f,
                         const u32* mraw){
  bool bf = is_bf(mraw);
  int i = blockIdx.x*256 + threadIdx.x;
  if (i < 1){ rsf[i] = fin(ldin(s_rs, i, bf)); return; }
  i -= 1;
  if (i < 1280){ bqf[i] = fin(ldin(s_bq, i, bf)); return; }
  i -= 1280;
  if (i < 2560){ bkvf[i] = fin(ldin(s_bkv, i, bf)); return; }
  i -= 2560;
  if (i < 40){ bsf[i] = fin(ldin(s_bs, i, bf)); return; }
  i -= 40;
  if (i < 1280){ bcf[i] = fin(ldin(s_bc, i, bf)); return; }
  i -= 1280;
  if (i < 5120){ b1f[i] = fin(ldin(s_b1, i, bf)); return; }
  i -= 5120;
  if (i < 1280){ b2f[i] = fin(ldin(s_b2, i, bf)); return; }
  i -= 1280;
  if (i < 1280){ g1f[i] = fin(ldin(s_g1, i, bf)); return; }
  i -= 1280;
  if (i < 1280){ g2f[i] = fin(ldin(s_g2, i, bf)); return; }
}

// legacy strided transpose (kept only for tiny Ws: N=8)
__global__ void k_wt(const void* src, u16* dst, int L, int K, int N, const u32* mraw){
  bool bf = is_bf(mraw);
  int i = blockIdx.x*256 + threadIdx.x;
  if (i >= L*K*N) return;
  int l = i/(K*N); int r = i%(K*N); int n = r/K; int k = r%K;
  dst[i] = f2b(fin(ldin(src, (size_t)l*K*N + (size_t)k*N + n, bf)));
}

// R7 (kept): coalesced weight transpose via 32x32 LDS tile.
// dst[l*ostr + (rowoff+n)*K + k] = src[l*K*N + k*N + n]. REQUIRES K,N multiples of 32.
__global__ void k_wt2(const void* src, u16* dst, int K, int N, int ostr, int rowoff,
                      const u32* mraw){
  bool bf = is_bf(mraw);
  __shared__ float tl[32][33];
  int nt = N >> 5, kt = K >> 5;
  int bid = blockIdx.x;
  int l = bid / (nt*kt); int r2 = bid % (nt*kt);
  int k0 = (r2 / nt) << 5, n0 = (r2 % nt) << 5;
  int tx = threadIdx.x & 31, ty = threadIdx.x >> 5;   // ty in 0..7
  size_t sbase = (size_t)l*K*N;
#pragma unroll
  for (int j = 0; j < 4; ++j){
    int k = k0 + ty + j*8;
    tl[ty + j*8][tx] = fin(ldin(src, sbase + (size_t)k*N + n0 + tx, bf));
  }
  __syncthreads();
#pragma unroll
  for (int j = 0; j < 4; ++j){
    int n = n0 + ty + j*8;
    dst[(size_t)l*ostr + (size_t)(rowoff + n)*K + k0 + tx] = f2b(tl[tx][ty + j*8]);
  }
}

// ---------------- RNG setup ----------------
__global__ void k_rng_setup(float* ABCbuf, u32* pickkeys){
#pragma clang fp contract(off)
  __shared__ float rawn[18][12];
  int s = threadIdx.x;
  if (s < 18){
    u32 ks0, ks1, o0, o1;
    tf2(0u, 42u, 0u, (u32)s, ks0, ks1);
    u32 ka0,ka1,kl0,kl1,kr0,kr1;
    tf2(ks0,ks1, 0u,0u, ka0,ka1);
    tf2(ks0,ks1, 0u,1u, kl0,kl1);
    tf2(ks0,ks1, 0u,2u, kr0,kr1);
    const float MINV = __uint_as_float(0xBF7FFFFFu);
    const float SQ2  = __uint_as_float(0x3FB504F3u);
    for (int j = 0; j < 12; ++j){
      tf2(ka0,ka1, 0u, (u32)j, o0, o1);
      u32 bits = o0 ^ o1;
      float f = __uint_as_float((bits >> 9) | 0x3F800000u) - 1.0f;
      float u = f*2.0f + MINV;
      u = fmaxf(MINV, u);
      rawn[s][j] = SQ2 * erfinv_xla(u);
    }
    u32 a0,a1;
    tf2(kl0,kl1, 0u,0u, a0,a1); pickkeys[(s*4+0)*2]=a0; pickkeys[(s*4+0)*2+1]=a1;
    tf2(kl0,kl1, 0u,1u, a0,a1); pickkeys[(s*4+1)*2]=a0; pickkeys[(s*4+1)*2+1]=a1;
    tf2(kr0,kr1, 0u,0u, a0,a1); pickkeys[(s*4+2)*2]=a0; pickkeys[(s*4+2)*2+1]=a1;
    tf2(kr0,kr1, 0u,1u, a0,a1); pickkeys[(s*4+3)*2]=a0; pickkeys[(s*4+3)*2+1]=a1;
  }
  __syncthreads();
  if (threadIdx.x == 0){
    float oldv[4][3];
    for (int b=0;b<4;b++){ oldv[b][0]=1.f; oldv[b][1]=1.f; oldv[b][2]=1.f; }
    for (int st = 0; st < 18; ++st){
      for (int b = 0; b < 4; ++b){
        float A0 = rawn[st][b*3+0], A1 = rawn[st][b*3+1], A2 = rawn[st][b*3+2];
        float na = fmaxf(sqrtf((A0*A0 + A1*A1) + A2*A2), 1e-12f);
        float p0 = oldv[b][0], p1 = oldv[b][1], p2 = oldv[b][2];
        float no = fmaxf(sqrtf((p0*p0 + p1*p1) + p2*p2), 1e-12f);
        float ang = (A0/na)*(p0/no) + (A1/na)*(p1/no) + (A2/na)*(p2/no);
        float sg = (ang > 0.f) ? 1.f : ((ang < 0.f) ? -1.f : 1.f);
        A0 *= sg; A1 *= sg; A2 *= sg;
        oldv[b][0]=A0; oldv[b][1]=A1; oldv[b][2]=A2;
        ABCbuf[(st*4+b)*3+0]=A0; ABCbuf[(st*4+b)*3+1]=A1; ABCbuf[(st*4+b)*3+2]=A2;
      }
    }
  }
}

__global__ void k_rng_bits(const u32* pickkeys, u32* bits){
  int id = blockIdx.x*256 + threadIdx.x;
  if (id >= 18*4*65536) return;
  int sp = id >> 16; u32 f = (u32)(id & 0xFFFF);
  u32 o0, o1;
  tf2(pickkeys[sp*2], pickkeys[sp*2+1], 0u, f, o0, o1);
  bits[id] = o0 ^ o1;
}

// ---- lightweight single-use PER-BATCH barrier (R7 verified: serialize 281->233us) ----
__device__ __forceinline__ void gbar16(u32* slot){
  __syncthreads();
  if (threadIdx.x == 0){
    __hip_atomic_fetch_add(slot, 1u, __ATOMIC_ACQ_REL, __HIP_MEMORY_SCOPE_AGENT);
    while (__hip_atomic_load(slot, __ATOMIC_RELAXED, __HIP_MEMORY_SCOPE_AGENT) < 16u)
      __builtin_amdgcn_s_sleep(2);
    (void)__hip_atomic_load(slot, __ATOMIC_ACQUIRE, __HIP_MEMORY_SCOPE_AGENT);
  }
  __syncthreads();
}

// ---------------- serialization: cooperative, 64 blocks (16 per batch) ----------------
// R7 verified (233 us): R4 structure + per-batch barriers.
__global__ __launch_bounds__(512) void k_serialize_coop(
    const float* __restrict__ coordsf, const float* __restrict__ maskf,
    const float* __restrict__ ABCbuf, const u32* __restrict__ bits,
    int* __restrict__ tkeys, double* __restrict__ sumpart, int* __restrict__ npart,
    u64* __restrict__ reckey, float4* __restrict__ recxyz, u32* __restrict__ gbars){
#pragma clang fp contract(off)
  __shared__ double sd[8];
  __shared__ int si[8];
  __shared__ u64 sp[4][8];
  int bx = blockIdx.x;
  int b = bx >> 4, blk = bx & 15;
  int t = threadIdx.x, wid = t >> 6, lane = t & 63;
  int base_i = blk*1024;
  u32* gb = gbars + b*64;   // 64 u32 per batch (256B) -> no cross-batch false sharing

  float p[2][3]; int tk[2]; u32 mb = 0;
#pragma unroll
  for (int j = 0; j < 2; ++j){
    int i = base_i + j*512 + t;
    size_t cb = (size_t)(b*16384 + i)*3;
    p[j][0] = coordsf[cb+0]; p[j][1] = coordsf[cb+1]; p[j][2] = coordsf[cb+2];
    if (maskf[b*16384 + i] > 0.f) mb |= (1u << j);
    tk[j] = 0;
  }
  // masked-count block partial (read once after first barrier)
  {
    int c = __popc(mb);
#pragma unroll
    for (int d = 1; d < 64; d <<= 1) c += __shfl_xor(c, d);
    if (lane == 0) si[wid] = c;
    __syncthreads();
    if (t == 0){ int cc = 0; for (int w = 0; w < 8; ++w) cc += si[w]; npart[b*16 + blk] = cc; }
  }
  float nplus = 0.f;

  for (int s = 0; s < 18; ++s){
    float A0 = ABCbuf[(s*4+b)*3+0], A1 = ABCbuf[(s*4+b)*3+1], A2 = ABCbuf[(s*4+b)*3+2];
    // ---- Phase A: projection + masked f64 partial sum ----
    float pr[2]; double acc = 0.0;
#pragma unroll
    for (int j = 0; j < 2; ++j){
      pr[j] = p[j][0]*A0 + p[j][1]*A1 + p[j][2]*A2;
      if ((mb >> j) & 1u) acc += (double)pr[j];
    }
#pragma unroll
    for (int d = 1; d < 64; d <<= 1) acc += __shfl_xor(acc, d);
    if (lane == 0) sd[wid] = acc;
    __syncthreads();
    if (t == 0){ double tt = 0.0; for (int w = 0; w < 8; ++w) tt += sd[w]; sumpart[b*16 + blk] = tt; }
    gbar16(&gb[s*2 + 0]);  // SYNC A (batch-local)

    // ---- Phase B: mean; signs/sides/tk; block argmin records (key + coords) ----
    if (s == 0){
      int cc = 0; for (int k2 = 0; k2 < 16; ++k2) cc += npart[b*16 + k2];
      nplus = (float)((double)cc + 1e-9);
    }
    double tot = 0.0;
    for (int k2 = 0; k2 < 16; ++k2) tot += sumpart[b*16 + k2];
    float mean = ((float)tot) / nplus;

    u32 sideL = 0, sideR = 0;
    int sc17 = 1 << (17 - s);
#pragma unroll
    for (int j = 0; j < 2; ++j){
      float pc = pr[j] - mean;
      int sc = (pc > 0.f) ? 1 : ((pc < 0.f) ? -1 : 0);
      tk[j] += sc * sc17;
      bool mi = (mb >> j) & 1u;
      if (mi && sc < 0) sideL |= (1u << j);
      if (mi && sc > 0) sideR |= (1u << j);
    }
    u64 mine[4]; int bj[4];
#pragma unroll
    for (int pk = 0; pk < 4; ++pk){ mine[pk] = ~0ULL; bj[pk] = 0; }
#pragma unroll
    for (int pk = 0; pk < 4; ++pk){
      const u32* bp = bits + (size_t)(s*4 + pk)*65536 + b*16384;
      u32 sm = (pk < 2) ? sideL : sideR;
#pragma unroll
      for (int j = 0; j < 2; ++j){
        if ((sm >> j) & 1u){
          int i = base_i + j*512 + t;
          u64 pkd = ((u64)(bp[i] >> 9) << 14) | (u32)i;
          if (pkd < mine[pk]){ mine[pk] = pkd; bj[pk] = j; }
        }
      }
    }
    u64 red[4];
#pragma unroll
    for (int pk = 0; pk < 4; ++pk) red[pk] = mine[pk];
#pragma unroll
    for (int d = 1; d < 64; d <<= 1)
#pragma unroll
      for (int pk = 0; pk < 4; ++pk) red[pk] = umin64(red[pk], __shfl_xor(red[pk], d));
    if (lane == 0){
#pragma unroll
      for (int pk = 0; pk < 4; ++pk) sp[pk][wid] = red[pk];
    }
    __syncthreads();
    u64 mm[4];
#pragma unroll
    for (int pk = 0; pk < 4; ++pk){
      u64 v = ~0ULL;
      for (int w = 0; w < 8; ++w) v = umin64(v, sp[pk][w]);
      mm[pk] = v;
    }
#pragma unroll
    for (int pk = 0; pk < 4; ++pk){
      int ri = ((b*4 + pk) << 4) + blk;
      if (mm[pk] == ~0ULL){
        if (t == 0){ reckey[ri] = ~0ULL; recxyz[ri] = make_float4(0.f, 0.f, 0.f, 0.f); }
      } else if (mine[pk] == mm[pk]){
        int j = bj[pk];
        reckey[ri] = mm[pk];
        recxyz[ri] = make_float4(p[j][0], p[j][1], p[j][2], 0.f);
      }
    }
    gbar16(&gb[s*2 + 1]);  // SYNC B (batch-local)

    // ---- Phase C: global argmin over 16 records (coords carried); update points ----
    float wc[4][3];
#pragma unroll
    for (int pk = 0; pk < 4; ++pk){
      u64 best = ~0ULL; int bk = 0;
      for (int k2 = 0; k2 < 16; ++k2){
        u64 kk = reckey[((b*4 + pk) << 4) + k2];
        if (kk < best){ best = kk; bk = k2; }
      }
      float4 c = recxyz[((b*4 + pk) << 4) + bk];
      wc[pk][0] = c.x; wc[pk][1] = c.y; wc[pk][2] = c.z;
    }
    float dl0=(wc[0][0]+wc[1][0])*0.5f, dl1=(wc[0][1]+wc[1][1])*0.5f, dl2=(wc[0][2]+wc[1][2])*0.5f;
    float dr0=(wc[2][0]+wc[3][0])*0.5f, dr1=(wc[2][1]+wc[3][1])*0.5f, dr2=(wc[2][2]+wc[3][2])*0.5f;
#pragma unroll
    for (int j = 0; j < 2; ++j){
      bool L = (sideL >> j) & 1u, R = (sideR >> j) & 1u;
      if (L){ p[j][0]-=dl0; p[j][1]-=dl1; p[j][2]-=dl2; }
      else if (R){ p[j][0]-=dr0; p[j][1]-=dr1; p[j][2]-=dr2; }
      else { p[j][0]=0.f; p[j][1]=0.f; p[j][2]=0.f; }
    }
  }
#pragma unroll
  for (int j = 0; j < 2; ++j){
    int i = base_i + j*512 + t;
    tkeys[b*16384 + i] = tk[j] + (((mb >> j) & 1u) ? 0 : 524288);
  }
}

// ---------------- 16384-element bitonic sort, 3 kernels ----------------
__global__ __launch_bounds__(1024) void k_bsort_phase1(u64* buf){
  __shared__ u64 sb[8192];
  u64* g = buf + (size_t)blockIdx.x*8192;
  int tid = threadIdx.x;
  for (int i = tid; i < 8192; i += 1024) sb[i] = g[i];
  int ab = blockIdx.x & 1;
  for (int k = 2; k <= 8192; k <<= 1){
    for (int j = k >> 1; j > 0; j >>= 1){
      __syncthreads();
      for (int pp = tid; pp < 4096; pp += 1024){
        int i  = ((pp & ~(j - 1)) << 1) | (pp & (j - 1));
        int ix = i | j;
        bool up = (k == 8192) ? (ab == 0) : ((i & k) == 0);
        u64 A = sb[i], B = sb[ix];
        if ((A > B) == up){ sb[i] = B; sb[ix] = A; }
      }
    }
  }
  __syncthreads();
  for (int i = tid; i < 8192; i += 1024) g[i] = sb[i];
}
__global__ __launch_bounds__(1024) void k_bsort_merge(u64* buf){
  u64* g = buf + (size_t)blockIdx.x*16384;
  for (int i = threadIdx.x; i < 8192; i += 1024){
    u64 A = g[i], B = g[i + 8192];
    if (A > B){ g[i] = B; g[i + 8192] = A; }
  }
}
__global__ __launch_bounds__(1024) void k_bsort_phase3(u64* buf){
  __shared__ u64 sb[8192];
  u64* g = buf + (size_t)blockIdx.x*8192;
  int tid = threadIdx.x;
  for (int i = tid; i < 8192; i += 1024) sb[i] = g[i];
  for (int j = 4096; j > 0; j >>= 1){
    __syncthreads();
    for (int pp = tid; pp < 4096; pp += 1024){
      int i  = ((pp & ~(j - 1)) << 1) | (pp & (j - 1));
      int ix = i | j;
      u64 A = sb[i], B = sb[ix];
      if (A > B){ sb[i] = B; sb[ix] = A; }
    }
  }
  __syncthreads();
  for (int i = tid; i < 8192; i += 1024) g[i] = sb[i];
}

__global__ void k_fill_sort(const int* tkeys, u64* sbuf){
  int id = blockIdx.x*256 + threadIdx.x;
  if (id >= 65536) return;
  u32 tv = (u32)(tkeys[id] + 262144);
  sbuf[id] = ((u64)tv << 14) | (u32)(id & 16383);
}
__global__ void k_unpack_sort(const u64* sbuf, int* idxb, int* revb){
  int id = blockIdx.x*256 + threadIdx.x;
  if (id >= 65536) return;
  int a = id >> 14, r = id & 16383;
  int orig = (int)(sbuf[id] & 16383u);
  idxb[id] = orig;
  revb[(a << 14) | orig] = r;
}

// R7 (kept): vectorized gather, 4 rows/block.
__global__ void k_gather(const void* xraw, const int* idxb, float* xbuf, const u32* mraw){
  bool bf = is_bf(mraw);
  int row = blockIdx.x*4 + (threadIdx.x >> 6), lane = threadIdx.x & 63;
  int b = row / 16512, rr = row % 16512;
  float4 v = {0.f, 0.f, 0.f, 0.f};
  if (rr < 16384){
    int src = idxb[b*16384 + rr];
    size_t base = (size_t)(b*16384 + src)*256 + lane*4;
    if (bf){
      ushort4 u = *(const ushort4*)((const u16*)xraw + base);
      v.x = fin(b2f(u.x)); v.y = fin(b2f(u.y)); v.z = fin(b2f(u.z)); v.w = fin(b2f(u.w));
    } else {
      float4 f = *(const float4*)((const float*)xraw + base);
      v.x = fin(f.x); v.y = fin(f.y); v.z = fin(f.z); v.w = fin(f.w);
    }
  }
  *(float4*)&xbuf[(size_t)row*256 + lane*4] = v;
}

__global__ void k_rmsnorm(const float* x, const float* g, u16* xn){
  int row = blockIdx.x*4 + (threadIdx.x >> 6);
  int lane = threadIdx.x & 63;
  float4 xv = *(const float4*)&x[(size_t)row*256 + lane*4];
  xv.x = fin(xv.x); xv.y = fin(xv.y); xv.z = fin(xv.z); xv.w = fin(xv.w);
  float ss = xv.x*xv.x + xv.y*xv.y + xv.z*xv.z + xv.w*xv.w;
#pragma unroll
  for (int d = 1; d < 64; d <<= 1) ss += __shfl_xor(ss, d);
  float sc = 1.0f / sqrtf(ss*(1.0f/256.0f) + 1e-6f);
  float4 gv = *(const float4*)&g[lane*4];
  ushort4 o4;
  o4.x = f2b(fin((xv.x*sc)*gv.x)); o4.y = f2b(fin((xv.y*sc)*gv.y));
  o4.z = f2b(fin((xv.z*sc)*gv.z)); o4.w = f2b(fin((xv.w*sc)*gv.w));
  *(ushort4*)&xn[(size_t)row*256 + lane*4] = o4;
}

// ---------------- bf16 MFMA GEMM: C = A(MxK) * Bt(NxK)^T + bias ----------------
// mode 0: f32 store; 1: f32 X += v*rs; 2: bf16 store; 3: gelu->bf16
// R6 VERIFIED CODEGEN (3471us) — restored byte-for-byte after R7's merged-QKV variant
// (extra C2 param + 5th mode branch) regressed all GEMM dispatches ~+750us total
// (co-compiled codegen hazard). Do NOT touch this kernel's signature/body without
// isolating the change.
// REQUIRES: M,N multiples of 128; K multiple of 64.
__global__ __launch_bounds__(256) void k_gemm(const u16* A, int lda, const u16* Bt, int ldb,
                                              int M, int N, int K, const float* bias,
                                              void* C, int ldc, int mode, const float* rsp){
  __shared__ __align__(16) u16 As[128*64];
  __shared__ __align__(16) u16 Bs[128*64];
  int tid = threadIdx.x;
  // --- XCD-aware bijective remap of the flat workgroup id ---
  int gx = (int)gridDim.x;
  int nwg = gx * (int)gridDim.y;
  int d = (int)blockIdx.y * gx + (int)blockIdx.x;   // dispatch-order flat id (x fastest)
  int q = nwg >> 3, r = nwg & 7;
  int xcd = d & 7, off = d >> 3;
  int wg = (xcd < r ? xcd*(q+1) : r*(q+1) + (xcd - r)*q) + off;
  int bxi = wg % gx, byi = wg / gx;
  int gm0 = byi*128, gn0 = bxi*128;
  int wv = tid >> 6, lane = tid & 63, q4 = lane >> 4, l16 = lane & 15;
  int wm = (wv >> 1)*64, wn = (wv & 1)*64;
  int lr = lane >> 3;
  int lcs = ((lane & 7) ^ lr) << 3;          // swizzled SOURCE col (u16)
  f32x4 acc[4][4];
#pragma unroll
  for (int i = 0; i < 4; ++i)
#pragma unroll
    for (int j = 0; j < 4; ++j) acc[i][j] = (f32x4){0.f,0.f,0.f,0.f};
  for (int k0 = 0; k0 < K; k0 += 64){
    __syncthreads();
#pragma unroll
    for (int i = 0; i < 4; ++i){
      int chunk = wv*4 + i;                  // 16 chunks of 8 rows
      int row = chunk*8 + lr;
      gload_lds16(&A[(size_t)(gm0+row)*lda + k0 + lcs],  &As[chunk*512]);
      gload_lds16(&Bt[(size_t)(gn0+row)*ldb + k0 + lcs], &Bs[chunk*512]);
    }
    __syncthreads();   // compiler drains vmcnt before s_barrier
#pragma unroll
    for (int ks = 0; ks < 64; ks += 32){
      int swc = ((((ks >> 3) + q4) ^ (l16 & 7)) << 3);
      s16x8 aF[4], bF[4];
#pragma unroll
      for (int mt = 0; mt < 4; ++mt) aF[mt] = *(const s16x8*)&As[(wm + mt*16 + l16)*64 + swc];
#pragma unroll
      for (int nt = 0; nt < 4; ++nt) bF[nt] = *(const s16x8*)&Bs[(wn + nt*16 + l16)*64 + swc];
#pragma unroll
      for (int mt = 0; mt < 4; ++mt)
#pragma unroll
        for (int nt = 0; nt < 4; ++nt)
          acc[mt][nt] = __builtin_amdgcn_mfma_f32_16x16x32_bf16(aF[mt], bF[nt], acc[mt][nt], 0, 0, 0);
    }
  }
  float rs = rsp[0];
  const float SQ2C = 1.41421356237f;
#pragma unroll
  for (int mt = 0; mt < 4; ++mt)
#pragma unroll
    for (int nt = 0; nt < 4; ++nt){
      int col = gn0 + wn + nt*16 + l16;
      float bi = bias[col];
#pragma unroll
      for (int rg = 0; rg < 4; ++rg){
        int row = gm0 + wm + mt*16 + q4*4 + rg;
        float v = fin(acc[mt][nt][rg] + bi);
        size_t off2 = (size_t)row*ldc + col;
        if (mode == 0) ((float*)C)[off2] = v;
        else if (mode == 1){ float* X = (float*)C; X[off2] = fin(X[off2] + v*rs); }
        else if (mode == 2) ((u16*)C)[off2] = f2b(v);
        else { float gl = 0.5f * v * (1.0f + erff(v / SQ2C)); ((u16*)C)[off2] = f2b(fin(gl)); }
      }
    }
}

// ---------------- score GEMM: C[M][8] = A[M][256] * Ws[8][256]^T + bias (f32) ------
__global__ __launch_bounds__(256) void k_gemm_score(const u16* __restrict__ A,
                                                    const u16* __restrict__ Bt,
                                                    int M, const float* __restrict__ bias,
                                                    float* __restrict__ C){
  __shared__ __align__(16) u16 As[128*72];
  int tid = threadIdx.x;
  int gm0 = blockIdx.x*128;
  int wv = tid >> 6, lane = tid & 63, q4 = lane >> 4, l16 = lane & 15;
  int wm = wv*32;                  // 4 waves x 32 rows
  int ar = tid >> 2, ac = tid & 3;
  f32x4 acc[2];
  acc[0] = (f32x4){0.f,0.f,0.f,0.f};
  acc[1] = (f32x4){0.f,0.f,0.f,0.f};
  for (int k0 = 0; k0 < 256; k0 += 64){
    __syncthreads();
#pragma unroll
    for (int ps = 0; ps < 2; ++ps){
      int r2 = ps*64 + ar;
      uint4 va0 = {0u,0u,0u,0u}, va1 = {0u,0u,0u,0u};
      if (gm0 + r2 < M){
        const u16* ap = &A[(size_t)(gm0+r2)*256 + k0 + ac*16];
        va0 = ((const uint4*)ap)[0];
        va1 = ((const uint4*)ap)[1];
      }
      *(uint4*)&As[r2*72 + ac*16]     = va0;
      *(uint4*)&As[r2*72 + ac*16 + 8] = va1;
    }
    __syncthreads();
#pragma unroll
    for (int ks = 0; ks < 64; ks += 32){
      s16x8 bF = (s16x8){0,0,0,0,0,0,0,0};
      if (l16 < 8) bF = *(const s16x8*)&Bt[(size_t)l16*256 + k0 + ks + q4*8];
      s16x8 aF0 = *(const s16x8*)&As[(wm + l16)*72 + ks + q4*8];
      s16x8 aF1 = *(const s16x8*)&As[(wm + 16 + l16)*72 + ks + q4*8];
      acc[0] = __builtin_amdgcn_mfma_f32_16x16x32_bf16(aF0, bF, acc[0], 0, 0, 0);
      acc[1] = __builtin_amdgcn_mfma_f32_16x16x32_bf16(aF1, bF, acc[1], 0, 0, 0);
    }
  }
  if (l16 < 8){
    float bi = bias[l16];
#pragma unroll
    for (int mt = 0; mt < 2; ++mt)
#pragma unroll
      for (int rg = 0; rg < 4; ++rg){
        int row = gm0 + wm + mt*16 + q4*4 + rg;
        if (row < M) C[(size_t)row*8 + l16] = fin(acc[mt][rg] + bi);
      }
  }
}

// ---------------- selection: local (drop 1 of 129) ----------------
__global__ __launch_bounds__(512) void k_sel_local(const float* scoreb, const float* maskf,
                                                   u32* sel, float* gateb){
  int s = blockIdx.x, h = threadIdx.x >> 6, lane = threadIdx.x & 63;
  int b = s >> 7, tt = s & 127;
  u64 pm = ~0ULL;
  for (int rep = 0; rep < 3; ++rep){
    int j = lane + rep*64;
    if (j < 129){
      int p = tt*129 + j;
      float m = (p < 16384) ? maskf[b*16384 + p] : 0.f;
      float ms = fin(scoreb[(size_t)(s*129 + j)*8 + h]) - (1.0f - m)*BIGF;
      u64 pk = ((u64)mono32(ms) << 9) | (u32)(511 - j);  // min val; tie -> drop larger j
      pm = umin64(pm, pk);
    }
  }
#pragma unroll
  for (int d = 1; d < 64; d <<= 1) pm = umin64(pm, __shfl_xor(pm, d));
  int dropped = 511 - (int)(pm & 511u);
  int sh = s*8 + h;
  for (int rep = 0; rep < 3; ++rep){
    int j = lane + rep*64;
    if (j < 129 && j != dropped){
      int slot = j - (j > dropped ? 1 : 0);
      int p = tt*129 + j;
      float m = (p < 16384) ? maskf[b*16384 + p] : 0.f;
      float ms = fin(scoreb[(size_t)(s*129 + j)*8 + h]) - (1.0f - m)*BIGF;
      sel[sh*128 + slot] = (u32)(s*129 + j);
      gateb[sh*128 + slot] = fin(sigm(ms));
    }
  }
}

// selection: global (top-128 of 16384 via sorted keys)
__global__ void k_fill_topk(const float* scoreb, const float* maskf, u64* sbuf){
  int id = blockIdx.x*256 + threadIdx.x;
  if (id >= 524288) return;
  int arr = id >> 14, i = id & 16383;
  int b = arr >> 3, h = arr & 7;
  float m = maskf[b*16384 + i];
  float ms = fin(scoreb[(size_t)(b*16512 + i)*8 + h]) - (1.0f - m)*BIGF;
  sbuf[id] = ((u64)(~mono32(ms)) << 14) | (u32)i;  // descending val, tie -> lower i
}
__global__ void k_sel_gemit(const u64* sbuf, const float* scoreb, const float* maskf,
                            u32* sel, float* gateb){
  int arr = blockIdx.x, tid = threadIdx.x;  // 32 x 128
  int b = arr >> 3, h = arr & 7;
  int j = (int)(sbuf[(size_t)arr*16384 + tid] & 16383u);
  float m = maskf[b*16384 + j];
  float ms = fin(scoreb[(size_t)(b*16512 + j)*8 + h]) - (1.0f - m)*BIGF;
  sel[arr*128 + tid] = (u32)(b*16512 + j);
  gateb[arr*128 + tid] = fin(sigm(ms));
}

// ---------------- fused MFMA attention (gathers gated K/V from vkv) ----------------
__global__ __launch_bounds__(256) void k_attn(const u16* qb, const u16* vkv,
                                              const u32* sel, const float* gateb,
                                              u16* xa, int gmode){
  __shared__ __align__(16) u16 Qsm[144*40];
  __shared__ __align__(16) u16 Ksm[128*40];
  __shared__ __align__(16) u16 Vtsm[32*136];
  __shared__ __align__(16) u16 Psm[4*16*136];
  int tid = threadIdx.x;
  int bx = blockIdx.x, h = blockIdx.y;
  int rows, rowbase, kvs, ntiles;
  if (gmode){
    int b = bx >> 7, rb = bx & 127;
    rows = 128; rowbase = b*16512 + rb*128; kvs = b; ntiles = 8;
  } else {
    rows = 129; rowbase = bx*129; kvs = bx; ntiles = 9;
  }
  int sh = kvs*8 + h;
  for (int t = tid; t < 144; t += 256) *(uint4*)&Qsm[t*40 + 32] = (uint4){0u,0u,0u,0u};
  if (tid < 128) *(uint4*)&Ksm[tid*40 + 32] = (uint4){0u,0u,0u,0u};
  if (tid < 32)  *(uint4*)&Vtsm[tid*136 + 128] = (uint4){0u,0u,0u,0u};
  if (tid < 64)  *(uint4*)&Psm[tid*136 + 128] = (uint4){0u,0u,0u,0u};
  for (int t = tid; t < 576; t += 256){
    int r = t >> 2, c = t & 3;
    uint4 v = {0u,0u,0u,0u};
    if (r < rows) v = *(const uint4*)&qb[(size_t)(rowbase + r)*256 + h*32 + c*8];
    *(uint4*)&Qsm[r*40 + c*8] = v;
  }
  for (int t = tid; t < 512; t += 256){
    int slot = t >> 2, part = t & 3;
    u32 rowi = sel[sh*128 + slot];
    float gv = fin(gateb[sh*128 + slot]);
    uint4 vk = *(const uint4*)&vkv[(size_t)rowi*512 + h*64 + part*8];
    uint4 wk; wk.x = gp2(vk.x, gv); wk.y = gp2(vk.y, gv); wk.z = gp2(vk.z, gv); wk.w = gp2(vk.w, gv);
    *(uint4*)&Ksm[slot*40 + part*8] = wk;
    uint4 vv = *(const uint4*)&vkv[(size_t)rowi*512 + h*64 + 32 + part*8];
    u32 vd[4] = {vv.x, vv.y, vv.z, vv.w};
#pragma unroll
    for (int e = 0; e < 4; ++e){
      float lo = fin(b2f((u16)(vd[e] & 0xFFFFu)) * gv), hi = fin(b2f((u16)(vd[e] >> 16)) * gv);
      Vtsm[(part*8 + e*2 + 0)*136 + slot] = f2b(lo);
      Vtsm[(part*8 + e*2 + 1)*136 + slot] = f2b(hi);
    }
  }
  __syncthreads();
  int wv = tid >> 6, lane = tid & 63, q4 = lane >> 4, l16 = lane & 15;
  u16* Pw = Psm + wv*(16*136);
  const float ATTSC = 0.17677669529663689f;
  f32x4 z = {0.f,0.f,0.f,0.f};
  for (int mt = wv; mt < ntiles; mt += 4){
    int m0 = mt*16;
    s16x8 aQ = *(const s16x8*)&Qsm[(m0 + l16)*40 + q4*8];
    f32x4 S[8];
#pragma unroll
    for (int nt = 0; nt < 8; ++nt){
      s16x8 bK = *(const s16x8*)&Ksm[(nt*16 + l16)*40 + q4*8];
      S[nt] = __builtin_amdgcn_mfma_f32_16x16x32_bf16(aQ, bK, z, 0, 0, 0);
    }
    float mx[4] = {-1e30f,-1e30f,-1e30f,-1e30f};
#pragma unroll
    for (int nt = 0; nt < 8; ++nt)
#pragma unroll
      for (int rg = 0; rg < 4; ++rg){ float v = fin(S[nt][rg])*ATTSC; S[nt][rg] = v; mx[rg] = fmaxf(mx[rg], v); }
#pragma unroll
    for (int d = 1; d < 16; d <<= 1)
#pragma unroll
      for (int rg = 0; rg < 4; ++rg) mx[rg] = fmaxf(mx[rg], __shfl_xor(mx[rg], d));
    float sm[4] = {0.f,0.f,0.f,0.f};
#pragma unroll
    for (int nt = 0; nt < 8; ++nt)
#pragma unroll
      for (int rg = 0; rg < 4; ++rg){ float e = __expf(S[nt][rg] - mx[rg]); S[nt][rg] = e; sm[rg] += e; }
#pragma unroll
    for (int d = 1; d < 16; d <<= 1)
#pragma unroll
      for (int rg = 0; rg < 4; ++rg) sm[rg] += __shfl_xor(sm[rg], d);
    float inv[4];
#pragma unroll
    for (int rg = 0; rg < 4; ++rg) inv[rg] = 1.0f/fmaxf(sm[rg], 1e-20f);
#pragma unroll
    for (int nt = 0; nt < 8; ++nt)
#pragma unroll
      for (int rg = 0; rg < 4; ++rg)
        Pw[(q4*4 + rg)*136 + nt*16 + l16] = f2b(fin(S[nt][rg]*inv[rg]));
    f32x4 O0 = z, O1 = z;
#pragma unroll
    for (int kq = 0; kq < 4; ++kq){
      s16x8 aP = *(const s16x8*)&Pw[l16*136 + kq*32 + q4*8];
      s16x8 b0 = *(const s16x8*)&Vtsm[l16*136 + kq*32 + q4*8];
      s16x8 b1 = *(const s16x8*)&Vtsm[(16 + l16)*136 + kq*32 + q4*8];
      O0 = __builtin_amdgcn_mfma_f32_16x16x32_bf16(aP, b0, O0, 0, 0, 0);
      O1 = __builtin_amdgcn_mfma_f32_16x16x32_bf16(aP, b1, O1, 0, 0, 0);
    }
#pragma unroll
    for (int rg = 0; rg < 4; ++rg){
      int r = m0 + q4*4 + rg;
      if (r < rows){
        size_t base = (size_t)(rowbase + r)*256 + h*32;
        xa[base + l16] = f2b(fin(O0[rg]));
        xa[base + 16 + l16] = f2b(fin(O1[rg]));
      }
    }
  }
}

// R7 (kept): vectorized output, 4 rows/block.
__global__ void k_output(const float* xbuf, const int* revb, void* out, const u32* mraw){
  bool bf = is_bf(mraw);
  int row = blockIdx.x*4 + (threadIdx.x >> 6), lane = threadIdx.x & 63;
  int b = row >> 14;
  int rank = revb[row];
  float4 f = *(const float4*)&xbuf[(size_t)(b*16512 + rank)*256 + lane*4];
  f.x = fin(f.x); f.y = fin(f.y); f.z = fin(f.z); f.w = fin(f.w);
  if (bf){
    ushort4 u; u.x = f2b(f.x); u.y = f2b(f.y); u.z = f2b(f.z); u.w = f2b(f.w);
    *(ushort4*)((u16*)out + (size_t)row*256 + lane*4) = u;
  } else {
    *(float4*)((float*)out + (size_t)row*256 + lane*4) = f;
  }
}

// =========================== host ===========================
extern "C" void kernel_launch(void* const* d_in, const int* in_sizes, int n_in,
                              void* d_out, int out_size, void* d_ws, size_t ws_size,
                              hipStream_t stream){
  (void)in_sizes; (void)n_in;
  const u32* mraw = (const u32*)d_in[2];
  char* wsp = (char*)d_ws;
  size_t o = 0;
  auto alloc = [&](size_t bytes)->void*{ void* p = (void*)(wsp + o); o += (bytes + 255) & ~(size_t)255; return p; };
  float* maskf   = (float*)alloc(65536u*4);
  float* coordsf = (float*)alloc(196608u*4);
  float* rsf     = (float*)alloc(256);
  float* bqf     = (float*)alloc(5*256*4);
  float* bkvf    = (float*)alloc(5*512*4);
  float* bsf     = (float*)alloc(5*8*4);
  float* bcf     = (float*)alloc(5*256*4);
  float* b1f     = (float*)alloc(5*1024*4);
  float* b2f     = (float*)alloc(5*256*4);
  float* g1f     = (float*)alloc(5*256*4);
  float* g2f     = (float*)alloc(5*256*4);
  u16* WqT  = (u16*)alloc((size_t)5*256*256*2);
  u16* WvT  = (u16*)alloc((size_t)5*512*256*2);
  u16* WsT  = (u16*)alloc((size_t)5*8*256*2);
  u16* WcT  = (u16*)alloc((size_t)5*256*256*2);
  u16* W1T  = (u16*)alloc((size_t)5*1024*256*2);
  u16* W2T  = (u16*)alloc((size_t)5*1024*256*2);
  float* ABCbuf = (float*)alloc(18*12*4);
  u32* pickkeys = (u32*)alloc(72*2*4);
  int* tkeys = (int*)alloc(65536u*4);
  int* idxb  = (int*)alloc(65536u*4);
  int* revb  = (int*)alloc(65536u*4);
  double* sumpart = (double*)alloc(64*8);
  int*    npart   = (int*)alloc(64*4);
  u64*    reckey  = (u64*)alloc(256*8);
  float4* recxyz  = (float4*)alloc(256*16);
  u32*    gbars   = (u32*)alloc(256*4);
  u64* sortbuf = (u64*)alloc((size_t)32*16384*8);
  float* xbuf = (float*)alloc((size_t)66048*256*4);
  u16* xn  = (u16*)alloc((size_t)66048*256*2);
  float* scoreb = (float*)alloc((size_t)66048*8*4);
  const size_t SZ_VKV = (size_t)66048*512*2;
  const size_t SZ_QB  = (size_t)66048*256*2;
  const size_t SZ_SEL = (size_t)4096*128*4;
  char* Sbase = (char*)alloc(SZ_VKV + SZ_QB + 2*SZ_SEL);
  u16* vkv    = (u16*)Sbase;
  u16* qb     = (u16*)(Sbase + SZ_VKV);
  u32* sel    = (u32*)(Sbase + SZ_VKV + SZ_QB);
  float* gateb= (float*)(Sbase + SZ_VKV + SZ_QB + SZ_SEL);
  u32* bitsb  = (u32*)Sbase;
  u16* ffb    = (u16*)Sbase;
  u16* xa     = qb;

  if (o > ws_size){
    k_fallback<<<dim3((out_size + 255)/256), 256, 0, stream>>>(d_out, out_size, mraw);
    return;
  }

  k_conv<<<dim3(256), 256, 0, stream>>>(d_in[2], maskf, 65536, mraw);
  k_conv<<<dim3(768), 256, 0, stream>>>(d_in[1], coordsf, 196608, mraw);
  k_conv_b<<<dim3(56), 256, 0, stream>>>(d_in[3], d_in[5], d_in[7], d_in[15], d_in[9],
                                         d_in[11], d_in[13], d_in[16], d_in[17],
                                         rsf, bqf, bkvf, bsf, bcf, b1f, b2f, g1f, g2f, mraw);
  // coalesced transposes (K,N multiples of 32); Ws (N=8) keeps the legacy path
  k_wt2<<<dim3(5*8*8),  256, 0, stream>>>(d_in[4],  WqT, 256, 256,  256*256, 0,  mraw);
  k_wt2<<<dim3(5*8*16), 256, 0, stream>>>(d_in[6],  WvT, 256, 512,  512*256, 0,  mraw);
  k_wt2<<<dim3(5*8*8),  256, 0, stream>>>(d_in[8],  WcT, 256, 256,  256*256, 0,  mraw);
  k_wt2<<<dim3(5*8*32), 256, 0, stream>>>(d_in[10], W1T, 256, 1024, 1024*256, 0, mraw);
  k_wt2<<<dim3(5*32*8), 256, 0, stream>>>(d_in[12], W2T, 1024, 256, 256*1024, 0, mraw);
  k_wt<<<dim3(40), 256, 0, stream>>>(d_in[14], WsT, 5, 256, 8, mraw);

  k_rng_setup<<<dim3(1), 64, 0, stream>>>(ABCbuf, pickkeys);
  k_rng_bits<<<dim3(18432), 256, 0, stream>>>(pickkeys, bitsb);
  k_zero<<<dim3(1), 256, 0, stream>>>(gbars, 256);
  {
    const float* a_coords = coordsf;
    const float* a_mask   = maskf;
    const float* a_abc    = ABCbuf;
    const u32*   a_bits   = bitsb;
    int*         a_tkeys  = tkeys;
    double*      a_sum    = sumpart;
    int*         a_np     = npart;
    u64*         a_rk     = reckey;
    float4*      a_rx     = recxyz;
    u32*         a_gb     = gbars;
    void* kargs[10];
    kargs[0] = (void*)&a_coords; kargs[1] = (void*)&a_mask; kargs[2] = (void*)&a_abc;
    kargs[3] = (void*)&a_bits;   kargs[4] = (void*)&a_tkeys;
    kargs[5] = (void*)&a_sum;    kargs[6] = (void*)&a_np;
    kargs[7] = (void*)&a_rk;     kargs[8] = (void*)&a_rx;
    kargs[9] = (void*)&a_gb;
    hipLaunchCooperativeKernel((void*)k_serialize_coop, dim3(64), dim3(512), kargs, 0, stream);
  }
  k_fill_sort<<<dim3(256), 256, 0, stream>>>(tkeys, sortbuf);
  k_bsort_phase1<<<dim3(8), 1024, 0, stream>>>(sortbuf);
  k_bsort_merge<<<dim3(4), 1024, 0, stream>>>(sortbuf);
  k_bsort_phase3<<<dim3(8), 1024, 0, stream>>>(sortbuf);
  k_unpack_sort<<<dim3(256), 256, 0, stream>>>(sortbuf, idxb, revb);
  k_gather<<<dim3(16512), 256, 0, stream>>>(d_in[0], idxb, xbuf, mraw);

  auto gemm = [&](const u16* A, int lda, const u16* Bt, int ldb, int M, int N, int K,
                  const float* bias, void* C, int ldc, int mode){
    dim3 g((N + 127)/128, (M + 127)/128);
    k_gemm<<<g, 256, 0, stream>>>(A, lda, Bt, ldb, M, N, K, bias, C, ldc, mode, rsf);
  };

  for (int l = 0; l < 5; ++l){
    bool local = (l < 4);
    k_rmsnorm<<<dim3(16512), 256, 0, stream>>>(xbuf, g1f + l*256, xn);
    gemm(xn, 256, WqT + (size_t)l*256*256, 256, 66048, 256, 256, bqf + l*256, qb, 256, 2);
    gemm(xn, 256, WvT + (size_t)l*512*256, 256, 66048, 512, 256, bkvf + l*512, vkv, 512, 2);
    k_gemm_score<<<dim3(516), 256, 0, stream>>>(xn, WsT + (size_t)l*8*256, 66048,
                                                bsf + l*8, scoreb);
    if (local){
      k_sel_local<<<dim3(512), 512, 0, stream>>>(scoreb, maskf, sel, gateb);
    } else {
      k_fill_topk<<<dim3(2048), 256, 0, stream>>>(scoreb, maskf, sortbuf);
      k_bsort_phase1<<<dim3(64), 1024, 0, stream>>>(sortbuf);
      k_bsort_merge<<<dim3(32), 1024, 0, stream>>>(sortbuf);
      k_bsort_phase3<<<dim3(64), 1024, 0, stream>>>(sortbuf);
      k_sel_gemit<<<dim3(32), 128, 0, stream>>>(sortbuf, scoreb, maskf, sel, gateb);
    }
    k_attn<<<dim3(512, 8), 256, 0, stream>>>(qb, vkv, sel, gateb, xa, local ? 0 : 1);
    gemm(xa, 256, WcT + (size_t)l*256*256, 256, 66048, 256, 256, bcf + l*256, xbuf, 256, 1);
    k_rmsnorm<<<dim3(16512), 256, 0, stream>>>(xbuf, g2f + l*256, xn);
    for (int half = 0; half < 2; ++half){
      const u16* Ah = xn + (size_t)half*33024*256;
      gemm(Ah, 256, W1T + (size_t)l*1024*256, 256, 33024, 1024, 256, b1f + l*1024, ffb, 1024, 3);
      gemm(ffb, 1024, W2T + (size_t)l*1024*256, 1024, 33024, 256, 1024, b2f + l*256,
           xbuf + (size_t)half*33024*256, 256, 1);
    }
  }
  k_output<<<dim3(16384), 256, 0, stream>>>(xbuf, revb, d_out, mraw);
}